// Round 1
// baseline (2741.303 us; speedup 1.0000x reference)
//
#include <hip/hip_runtime.h>
#include <hip/hip_bf16.h>

#define NROWS 16384
#define HDIM  2048
#define HHALF 1024
#define NC    32

// ---------------------------------------------------------------------------
// Workspace layout (bytes):
// [0,     64K)   idx     int[16384]
// [64K,   64K+128) counts float[32]
// [128K,  384K)  kcent   float[32*2048]   (sums -> means in place)
// [384K,  640K)  vcent
// [640K,  896K)  hk      float[32*2048]   (transform hidden, k)
// [896K, 1152K)  hv
// [1152K,1408K)  tck     float[32*2048]   (transformed centroids)
// [1408K,1664K)  tcv
// ---------------------------------------------------------------------------

// Kernel 1: fused scores MLP + argmax.
// Block = 256 threads, 64 rows of K. Loops hidden dim in 64-wide j-tiles;
// for each j-tile, a 64x64 fp32 tile GEMM over k=2048 (LDS-staged), then
// bias+ReLU into LDS and immediate projection onto cw2 (32 centroids)
// accumulated in registers. Never materializes the [N,1024] hidden.
__global__ __launch_bounds__(256) void k_scores(
    const float* __restrict__ K, const float* __restrict__ cw1,
    const float* __restrict__ cb1, const float* __restrict__ cw2,
    const float* __restrict__ cb2, int* __restrict__ idx)
{
    __shared__ float Ks[64][65];
    __shared__ float Ws[64][65];
    __shared__ float Hs[64][65];
    __shared__ float W2s[NC][65];
    __shared__ float Sc[64][NC];

    const int tid  = threadIdx.x;
    const int row0 = blockIdx.x * 64;
    const int ti = tid & 15;   // i-group (rows), i = ti*4+di
    const int tj = tid >> 4;   // j-group (hidden), j = tj*4+dj
    const int si  = tid & 63;        // scores: row owned
    const int sc0 = (tid >> 6) * 8;  // scores: centroid group base

    float sacc[8];
#pragma unroll
    for (int q = 0; q < 8; ++q) sacc[q] = 0.f;

    for (int jt = 0; jt < 16; ++jt) {
        const int j0 = jt * 64;
        __syncthreads();  // protect W2s/Hs from previous j-tile readers
        // stage cw2 tile [32][64]
        for (int e = tid; e < NC * 64; e += 256) {
            int c = e >> 6, j = e & 63;
            W2s[c][j] = cw2[c * HHALF + j0 + j];
        }
        float hacc[4][4];
#pragma unroll
        for (int a = 0; a < 4; ++a)
#pragma unroll
            for (int b = 0; b < 4; ++b) hacc[a][b] = 0.f;

        for (int kt = 0; kt < 32; ++kt) {
            const int k0 = kt * 64;
            __syncthreads();  // previous compute done before overwrite
            {
                const int f4 = tid & 15;   // float4 column 0..15
                const int r  = tid >> 4;   // 0..15
#pragma unroll
                for (int rr = 0; rr < 4; ++rr) {
                    const int row = r + rr * 16;
                    float4 kv = *(const float4*)&K[(size_t)(row0 + row) * HDIM + k0 + f4 * 4];
                    Ks[row][f4 * 4 + 0] = kv.x; Ks[row][f4 * 4 + 1] = kv.y;
                    Ks[row][f4 * 4 + 2] = kv.z; Ks[row][f4 * 4 + 3] = kv.w;
                    float4 wv = *(const float4*)&cw1[(size_t)(j0 + row) * HDIM + k0 + f4 * 4];
                    Ws[row][f4 * 4 + 0] = wv.x; Ws[row][f4 * 4 + 1] = wv.y;
                    Ws[row][f4 * 4 + 2] = wv.z; Ws[row][f4 * 4 + 3] = wv.w;
                }
            }
            __syncthreads();
#pragma unroll 8
            for (int k = 0; k < 64; ++k) {
                float a[4], b[4];
#pragma unroll
                for (int d = 0; d < 4; ++d) a[d] = Ks[ti * 4 + d][k];
#pragma unroll
                for (int d = 0; d < 4; ++d) b[d] = Ws[tj * 4 + d][k];
#pragma unroll
                for (int di = 0; di < 4; ++di)
#pragma unroll
                    for (int dj = 0; dj < 4; ++dj)
                        hacc[di][dj] += a[di] * b[dj];
            }
        }
        // bias + ReLU -> Hs
#pragma unroll
        for (int di = 0; di < 4; ++di)
#pragma unroll
            for (int dj = 0; dj < 4; ++dj) {
                float h = hacc[di][dj] + cb1[j0 + tj * 4 + dj];
                Hs[ti * 4 + di][tj * 4 + dj] = fmaxf(h, 0.f);
            }
        __syncthreads();
        // project this 64-wide hidden slice onto the 32 centroids
        for (int j = 0; j < 64; ++j) {
            float h = Hs[si][j];
#pragma unroll
            for (int q = 0; q < 8; ++q)
                sacc[q] += h * W2s[sc0 + q][j];
        }
    }
    // finalize scores and argmax (first-max semantics, like jnp.argmax)
#pragma unroll
    for (int q = 0; q < 8; ++q)
        Sc[si][sc0 + q] = sacc[q] + cb2[sc0 + q];
    __syncthreads();
    if (tid < 64) {
        float best = Sc[tid][0];
        int bi = 0;
        for (int c = 1; c < NC; ++c) {
            float v = Sc[tid][c];
            if (v > best) { best = v; bi = c; }
        }
        idx[row0 + tid] = bi;
    }
}

// Kernel 2: counts histogram
__global__ __launch_bounds__(256) void k_counts(const int* __restrict__ idx,
                                                float* __restrict__ counts)
{
    __shared__ int hist[NC];
    if (threadIdx.x < NC) hist[threadIdx.x] = 0;
    __syncthreads();
    const int i = blockIdx.x * 256 + threadIdx.x;
    atomicAdd(&hist[idx[i]], 1);
    __syncthreads();
    if (threadIdx.x < NC)
        atomicAdd(&counts[threadIdx.x], (float)hist[threadIdx.x]);
}

// Kernel 3: segment sums of K and V into kcent/vcent (pre-zeroed).
// Grid = 8 H-slices x 32 row-chunks. LDS per-centroid partials, then
// one global atomic per (c, col) per block.
__global__ __launch_bounds__(256) void k_segsum(
    const float* __restrict__ K, const float* __restrict__ V,
    const int* __restrict__ idx, float* __restrict__ ksum,
    float* __restrict__ vsum)
{
    __shared__ float ks_l[NC][256];
    __shared__ float vs_l[NC][256];
    const int hs  = blockIdx.x & 7;
    const int rc  = blockIdx.x >> 3;
    const int col = threadIdx.x;
    const int hb  = hs * 256;
#pragma unroll
    for (int c = 0; c < NC; ++c) { ks_l[c][col] = 0.f; vs_l[c][col] = 0.f; }
    __syncthreads();
    const int r0 = rc * 512;
    for (int r = r0; r < r0 + 512; ++r) {
        const int c = idx[r];
        atomicAdd(&ks_l[c][col], K[(size_t)r * HDIM + hb + col]);
        atomicAdd(&vs_l[c][col], V[(size_t)r * HDIM + hb + col]);
    }
    __syncthreads();
    for (int c = 0; c < NC; ++c) {
        atomicAdd(&ksum[c * HDIM + hb + col], ks_l[c][col]);
        atomicAdd(&vsum[c * HDIM + hb + col], vs_l[c][col]);
    }
}

// Kernel 4a: sums -> means (in place)
__global__ __launch_bounds__(256) void k_final1(float* __restrict__ kc,
                                                float* __restrict__ vc,
                                                const float* __restrict__ counts)
{
    const int e = blockIdx.x * 256 + threadIdx.x;  // 65536 total
    const int c = e >> 11;
    const float denom = fmaxf(counts[c], 1.f);
    kc[e] /= denom;
    vc[e] /= denom;
}

// Kernel 4b: reseed empty centroids from most-populated one (+0.1*noise).
// Separate launch so kc[src] is already finalized (no race).
__global__ __launch_bounds__(256) void k_final2(
    float* __restrict__ kc, float* __restrict__ vc,
    const float* __restrict__ counts, const float* __restrict__ nk,
    const float* __restrict__ nv)
{
    const int e = blockIdx.x * 256 + threadIdx.x;
    const int c = e >> 11;
    const int h = e & 2047;
    if (counts[c] == 0.f) {
        int src = 0;
        float best = counts[0];
        for (int j = 1; j < NC; ++j) {
            float v = counts[j];
            if (v > best) { best = v; src = j; }
        }
        kc[e] = kc[src * HDIM + h] + 0.1f * nk[e];
        vc[e] = vc[src * HDIM + h] + 0.1f * nv[e];
    }
}

// Kernel 5: one MLP layer over the 32 centroids (both k and v via blockIdx.y).
// out[32][2048] = (relu?) (X[32][2048] @ W[2048][2048]^T + b)
__global__ __launch_bounds__(256) void k_mlp(
    const float* __restrict__ Xk, const float* __restrict__ Xv,
    const float* __restrict__ W, const float* __restrict__ bias,
    float* __restrict__ Ok, float* __restrict__ Ov, int relu)
{
    __shared__ float Xs[32][65];
    __shared__ float Wt[64][65];
    const float* X = blockIdx.y ? Xv : Xk;
    float* O       = blockIdx.y ? Ov : Ok;
    const int tid   = threadIdx.x;
    const int jbase = blockIdx.x * 64;
    const int ti = tid & 7;    // i = ti*4+d   (32 rows)
    const int tj = tid >> 3;   // j = tj*2+e   (64 cols)
    float acc[4][2];
#pragma unroll
    for (int a = 0; a < 4; ++a) { acc[a][0] = 0.f; acc[a][1] = 0.f; }

    for (int kt = 0; kt < 32; ++kt) {
        const int k0 = kt * 64;
        __syncthreads();
        {
            const int f4 = tid & 15;
            const int r  = tid >> 4;
#pragma unroll
            for (int rr = 0; rr < 2; ++rr) {
                const int row = r + rr * 16;
                float4 xv = *(const float4*)&X[(size_t)row * HDIM + k0 + f4 * 4];
                Xs[row][f4 * 4 + 0] = xv.x; Xs[row][f4 * 4 + 1] = xv.y;
                Xs[row][f4 * 4 + 2] = xv.z; Xs[row][f4 * 4 + 3] = xv.w;
            }
#pragma unroll
            for (int rr = 0; rr < 4; ++rr) {
                const int row = r + rr * 16;
                float4 wv = *(const float4*)&W[(size_t)(jbase + row) * HDIM + k0 + f4 * 4];
                Wt[row][f4 * 4 + 0] = wv.x; Wt[row][f4 * 4 + 1] = wv.y;
                Wt[row][f4 * 4 + 2] = wv.z; Wt[row][f4 * 4 + 3] = wv.w;
            }
        }
        __syncthreads();
#pragma unroll 8
        for (int k = 0; k < 64; ++k) {
            float a[4], b[2];
#pragma unroll
            for (int d = 0; d < 4; ++d) a[d] = Xs[ti * 4 + d][k];
#pragma unroll
            for (int d = 0; d < 2; ++d) b[d] = Wt[tj * 2 + d][k];
#pragma unroll
            for (int d = 0; d < 4; ++d)
#pragma unroll
                for (int e2 = 0; e2 < 2; ++e2)
                    acc[d][e2] += a[d] * b[e2];
        }
    }
#pragma unroll
    for (int d = 0; d < 4; ++d)
#pragma unroll
        for (int e2 = 0; e2 < 2; ++e2) {
            const int i = ti * 4 + d;
            const int j = jbase + tj * 2 + e2;
            float v = acc[d][e2] + bias[j];
            if (relu) v = fmaxf(v, 0.f);
            O[(size_t)i * HDIM + j] = v;
        }
}

// Kernel 6: output assembly. 90% of rows pass keys/values through; rest
// gather the transformed centroid row.
__global__ __launch_bounds__(256) void k_out(
    const float* __restrict__ K, const float* __restrict__ V,
    const float* __restrict__ imp, const int* __restrict__ idx,
    const float* __restrict__ tck, const float* __restrict__ tcv,
    float* __restrict__ ok, float* __restrict__ ov)
{
    const size_t total = (size_t)NROWS * (HDIM / 4);
    for (size_t e = (size_t)blockIdx.x * 256 + threadIdx.x; e < total;
         e += (size_t)gridDim.x * 256) {
        const int r = (int)(e >> 9);
        const int q = (int)(e & 511);
        const bool pass = imp[r] > 0.1f;
        const int c = idx[r];
        const float4* sk = pass ? (const float4*)&K[(size_t)r * HDIM]
                                : (const float4*)&tck[(size_t)c * HDIM];
        const float4* sv = pass ? (const float4*)&V[(size_t)r * HDIM]
                                : (const float4*)&tcv[(size_t)c * HDIM];
        ((float4*)ok)[e] = sk[q];
        ((float4*)ov)[e] = sv[q];
    }
}

extern "C" void kernel_launch(void* const* d_in, const int* in_sizes, int n_in,
                              void* d_out, int out_size, void* d_ws,
                              size_t ws_size, hipStream_t stream)
{
    (void)in_sizes; (void)n_in; (void)out_size; (void)ws_size;
    const float* keys   = (const float*)d_in[0];
    const float* values = (const float*)d_in[1];
    const float* imp    = (const float*)d_in[2];
    const float* cw1    = (const float*)d_in[3];
    const float* cb1    = (const float*)d_in[4];
    const float* cw2    = (const float*)d_in[5];
    const float* cb2    = (const float*)d_in[6];
    const float* tw1    = (const float*)d_in[7];
    const float* tb1    = (const float*)d_in[8];
    const float* tw2    = (const float*)d_in[9];
    const float* tb2    = (const float*)d_in[10];
    const float* nk     = (const float*)d_in[11];
    const float* nv     = (const float*)d_in[12];

    char* ws = (char*)d_ws;
    int*   idx    = (int*)ws;
    float* counts = (float*)(ws + (64 << 10));
    float* kcent  = (float*)(ws + (128 << 10));
    float* vcent  = (float*)(ws + (384 << 10));
    float* hk     = (float*)(ws + (640 << 10));
    float* hv     = (float*)(ws + (896 << 10));
    float* tck    = (float*)(ws + (1152 << 10));
    float* tcv    = (float*)(ws + (1408 << 10));
    float* ok = (float*)d_out;
    float* ov = ok + (size_t)NROWS * HDIM;

    // zero counts + kcent + vcent (atomic accumulation targets)
    hipMemsetAsync(ws + (64 << 10), 0, (640 - 64) << 10, stream);

    k_scores<<<NROWS / 64, 256, 0, stream>>>(keys, cw1, cb1, cw2, cb2, idx);
    k_counts<<<NROWS / 256, 256, 0, stream>>>(idx, counts);
    k_segsum<<<256, 256, 0, stream>>>(keys, values, idx, kcent, vcent);
    k_final1<<<(NC * HDIM) / 256, 256, 0, stream>>>(kcent, vcent, counts);
    k_final2<<<(NC * HDIM) / 256, 256, 0, stream>>>(kcent, vcent, counts, nk, nv);
    k_mlp<<<dim3(HDIM / 64, 2), 256, 0, stream>>>(kcent, vcent, tw1, tb1, hk, hv, 1);
    k_mlp<<<dim3(HDIM / 64, 2), 256, 0, stream>>>(hk, hv, tw2, tb2, tck, tcv, 0);
    k_out<<<2048, 256, 0, stream>>>(keys, values, imp, idx, tck, tcv, ok, ov);
}

// Round 2
// 1452.465 us; speedup vs baseline: 1.8873x; 1.8873x over previous
//
#include <hip/hip_runtime.h>
#include <hip/hip_bf16.h>

#define NROWS 16384
#define HDIM  2048
#define HHALF 1024
#define NC    32
#define REFINE_TH 0.015625f
#define REFINE_CAP 2048

typedef __attribute__((ext_vector_type(8)))  short  short8;
typedef __attribute__((ext_vector_type(16))) float  f32x16;

static __device__ __forceinline__ short f2bf(float f) {
    __hip_bfloat16 h = __float2bfloat16(f);
    return *(short*)&h;
}
static __device__ __forceinline__ float bf2f(short s) {
    union { unsigned int i; float f; } v;
    v.i = ((unsigned int)(unsigned short)s) << 16;
    return v.f;
}

// ---------------------------------------------------------------------------
// Workspace layout (bytes):
// [0,     64K)   idx        int[16384]
// [64K,   +128)  counts     float[32]
// [128K,  384K)  kcent      float[32*2048]
// [384K,  640K)  vcent
// [640K,  896K)  hk
// [896K, 1152K)  hv
// [1152K,1408K)  tck
// [1408K,1664K)  tcv
// [1664K, +4)    refine_cnt int
// [1664K+4K, +8K) refine_rows int[2048]
// [1664K+12K, +256K) scoresR float[2048*32]
// ---------------------------------------------------------------------------

// Kernel 1: scores MLP via split-bf16 MFMA + argmax + margin flagging.
// Grid 256 blocks x 64 rows. j-tile = 128 (8 iters), K-tile = 64.
// Waves 2x2: wave (wr,wj) computes rows wr*32..+32, cols wj*64..+64
// as 2 accum tiles of 32x32x16 MFMA; 3 split MFMAs (hh,hl,lh) per step.
__global__ __launch_bounds__(256) void k_scores_mfma(
    const float* __restrict__ K, const float* __restrict__ cw1,
    const float* __restrict__ cb1, const float* __restrict__ cw2,
    const float* __restrict__ cb2, int* __restrict__ idx,
    int* __restrict__ rcnt, int* __restrict__ rrows)
{
    __shared__ alignas(16) short KsH[64][72], KsL[64][72];    // [row][k] KT=64
    __shared__ alignas(16) short WsH[128][72], WsL[128][72];  // [j][k]
    __shared__ alignas(16) short Hs[64][136];                 // hidden bf16-hi [row][j]
    __shared__ alignas(16) short BsH[32][136], BsL[32][136];  // cw2 slice [c][j]
    __shared__ float ScL[2][64][32];

    const int tid  = threadIdx.x;
    const int row0 = blockIdx.x * 64;
    const int w    = tid >> 6;
    const int lane = tid & 63;
    const int wr   = w & 1;    // row half
    const int wj   = w >> 1;   // j half
    const int l31  = lane & 31;
    const int lhi  = lane >> 5;

    f32x16 sacc = {};  // layer-2 partial scores (this wave's 32 rows x 32 c, k-half wj)

    for (int jt = 0; jt < 8; ++jt) {
        const int jbase = jt * 128;
        f32x16 acc0 = {}, acc1 = {};

        for (int kt = 0; kt < 32; ++kt) {
            const int k0 = kt * 64;
            __syncthreads();
            // stage K tile 64x64 fp32 -> hi/lo bf16
            {
                const int r  = tid >> 2;
                const int kq = (tid & 3) * 16;
                const float* src = &K[(size_t)(row0 + r) * HDIM + k0 + kq];
                short hi[16], lo[16];
#pragma unroll
                for (int q = 0; q < 4; ++q) {
                    float4 v = *(const float4*)(src + q * 4);
                    float f[4] = {v.x, v.y, v.z, v.w};
#pragma unroll
                    for (int e = 0; e < 4; ++e) {
                        short h = f2bf(f[e]);
                        hi[q * 4 + e] = h;
                        lo[q * 4 + e] = f2bf(f[e] - bf2f(h));
                    }
                }
                *(short8*)&KsH[r][kq]     = *(short8*)&hi[0];
                *(short8*)&KsH[r][kq + 8] = *(short8*)&hi[8];
                *(short8*)&KsL[r][kq]     = *(short8*)&lo[0];
                *(short8*)&KsL[r][kq + 8] = *(short8*)&lo[8];
            }
            // stage W tile 128x64 fp32 -> hi/lo
            {
                const int j  = tid >> 1;
                const int kh = (tid & 1) * 32;
                const float* src = &cw1[(size_t)(jbase + j) * HDIM + k0 + kh];
                short hi[32], lo[32];
#pragma unroll
                for (int q = 0; q < 8; ++q) {
                    float4 v = *(const float4*)(src + q * 4);
                    float f[4] = {v.x, v.y, v.z, v.w};
#pragma unroll
                    for (int e = 0; e < 4; ++e) {
                        short h = f2bf(f[e]);
                        hi[q * 4 + e] = h;
                        lo[q * 4 + e] = f2bf(f[e] - bf2f(h));
                    }
                }
#pragma unroll
                for (int q = 0; q < 4; ++q) {
                    *(short8*)&WsH[j][kh + q * 8] = *(short8*)&hi[q * 8];
                    *(short8*)&WsL[j][kh + q * 8] = *(short8*)&lo[q * 8];
                }
            }
            __syncthreads();
            // 4 k-steps of 16
#pragma unroll
            for (int ks = 0; ks < 4; ++ks) {
                const int kA = ks * 16 + lhi * 8;
                short8 aH = *(short8*)&KsH[wr * 32 + l31][kA];
                short8 aL = *(short8*)&KsL[wr * 32 + l31][kA];
                {
                    const int jB = wj * 64 + l31;
                    short8 bH = *(short8*)&WsH[jB][kA];
                    short8 bL = *(short8*)&WsL[jB][kA];
                    acc0 = __builtin_amdgcn_mfma_f32_32x32x16_bf16(aH, bH, acc0, 0, 0, 0);
                    acc0 = __builtin_amdgcn_mfma_f32_32x32x16_bf16(aH, bL, acc0, 0, 0, 0);
                    acc0 = __builtin_amdgcn_mfma_f32_32x32x16_bf16(aL, bH, acc0, 0, 0, 0);
                }
                {
                    const int jB = wj * 64 + 32 + l31;
                    short8 bH = *(short8*)&WsH[jB][kA];
                    short8 bL = *(short8*)&WsL[jB][kA];
                    acc1 = __builtin_amdgcn_mfma_f32_32x32x16_bf16(aH, bH, acc1, 0, 0, 0);
                    acc1 = __builtin_amdgcn_mfma_f32_32x32x16_bf16(aH, bL, acc1, 0, 0, 0);
                    acc1 = __builtin_amdgcn_mfma_f32_32x32x16_bf16(aL, bH, acc1, 0, 0, 0);
                }
            }
        }
        // bias + relu -> Hs (bf16 hi), C/D layout: col=lane&31, row=(r&3)+8*(r>>2)+4*lhi
        __syncthreads();  // all waves done reading Ks/Ws before Hs writers race? (Hs separate; this protects prev jt's Bs readers)
#pragma unroll
        for (int jc = 0; jc < 2; ++jc) {
            const int jL = wj * 64 + jc * 32 + l31;
            const float bias = cb1[jbase + jL];
            const f32x16 a = jc ? acc1 : acc0;
#pragma unroll
            for (int r = 0; r < 16; ++r) {
                const int rowL = wr * 32 + (r & 3) + 8 * (r >> 2) + 4 * lhi;
                float h = a[r] + bias;
                Hs[rowL][jL] = f2bf(fmaxf(h, 0.f));
            }
        }
        // stage cw2 slice [32 c][128 j] hi/lo
        {
            const int c  = tid >> 3;
            const int jq = (tid & 7) * 16;
            const float* src = &cw2[(size_t)c * HHALF + jbase + jq];
            short hi[16], lo[16];
#pragma unroll
            for (int q = 0; q < 4; ++q) {
                float4 v = *(const float4*)(src + q * 4);
                float f[4] = {v.x, v.y, v.z, v.w};
#pragma unroll
                for (int e = 0; e < 4; ++e) {
                    short h = f2bf(f[e]);
                    hi[q * 4 + e] = h;
                    lo[q * 4 + e] = f2bf(f[e] - bf2f(h));
                }
            }
            *(short8*)&BsH[c][jq]     = *(short8*)&hi[0];
            *(short8*)&BsH[c][jq + 8] = *(short8*)&hi[8];
            *(short8*)&BsL[c][jq]     = *(short8*)&lo[0];
            *(short8*)&BsL[c][jq + 8] = *(short8*)&lo[8];
        }
        __syncthreads();
        // layer-2: wave (wr,wj): rows wr*32..+32, k (=j) range wj*64..+64
#pragma unroll
        for (int ks = 0; ks < 4; ++ks) {
            const int kk = wj * 64 + ks * 16 + lhi * 8;
            short8 aH = *(short8*)&Hs[wr * 32 + l31][kk];
            short8 bH = *(short8*)&BsH[l31][kk];
            short8 bL = *(short8*)&BsL[l31][kk];
            sacc = __builtin_amdgcn_mfma_f32_32x32x16_bf16(aH, bH, sacc, 0, 0, 0);
            sacc = __builtin_amdgcn_mfma_f32_32x32x16_bf16(aH, bL, sacc, 0, 0, 0);
        }
    }
    // reduce the two k-halves, add cb2, argmax + margin
#pragma unroll
    for (int r = 0; r < 16; ++r) {
        const int rowL = wr * 32 + (r & 3) + 8 * (r >> 2) + 4 * lhi;
        ScL[wj][rowL][l31] = sacc[r];
    }
    __syncthreads();
    if (tid < 64) {
        float best = -3.4e38f, second = -3.4e38f;
        int bi = 0;
        for (int c = 0; c < NC; ++c) {
            float v = ScL[0][tid][c] + ScL[1][tid][c] + cb2[c];
            if (v > best) { second = best; best = v; bi = c; }
            else if (v > second) second = v;
        }
        idx[row0 + tid] = bi;
        if (best - second < REFINE_TH) {
            int slot = atomicAdd(rcnt, 1);
            if (slot < REFINE_CAP) rrows[slot] = row0 + tid;
        }
    }
}

// Kernel 1b: exact fp32 recompute of scores for flagged rows.
// Grid-stride over units = ceil(cnt/64) x 16 j-tiles of 64. Partial scores
// atomically accumulated into scoresR[slot*32+c].
__global__ __launch_bounds__(256) void k_refine_gemm(
    const float* __restrict__ K, const float* __restrict__ cw1,
    const float* __restrict__ cb1, const float* __restrict__ cw2,
    const int* __restrict__ rcnt, const int* __restrict__ rrows,
    float* __restrict__ scoresR)
{
    const int cnt = min(*rcnt, REFINE_CAP);
    if (cnt == 0) return;
    const int units = ((cnt + 63) >> 6) * 16;
    __shared__ float KsT[64][68];  // [k][row]
    __shared__ float WsT[64][68];  // [k][j]
    __shared__ float Hs2[64][68];  // [row][j]
    __shared__ float W2s[NC][68];  // [c][j]

    const int tid = threadIdx.x;
    const int ti = tid & 15, tj = tid >> 4;
    const int si = tid & 63, sc0 = (tid >> 6) * 8;

    for (int u = blockIdx.x; u < units; u += gridDim.x) {
        const int rc = u >> 4, jt = u & 15, j0 = jt * 64;
        const int M = min(cnt - rc * 64, 64);

        float hacc[4][4];
#pragma unroll
        for (int a = 0; a < 4; ++a)
#pragma unroll
            for (int b = 0; b < 4; ++b) hacc[a][b] = 0.f;

        for (int kt = 0; kt < 32; ++kt) {
            const int k0 = kt * 64;
            __syncthreads();
            {
                const int r  = tid >> 2;
                const int kb = (tid & 3) * 16;
                const int grow = rrows[rc * 64 + min(r, M - 1)];
#pragma unroll
                for (int q = 0; q < 4; ++q) {
                    float4 v = *(const float4*)&K[(size_t)grow * HDIM + k0 + kb + q * 4];
                    KsT[kb + q * 4 + 0][r] = v.x; KsT[kb + q * 4 + 1][r] = v.y;
                    KsT[kb + q * 4 + 2][r] = v.z; KsT[kb + q * 4 + 3][r] = v.w;
                }
                const int j = tid >> 2;
#pragma unroll
                for (int q = 0; q < 4; ++q) {
                    float4 v = *(const float4*)&cw1[(size_t)(j0 + j) * HDIM + k0 + kb + q * 4];
                    WsT[kb + q * 4 + 0][j] = v.x; WsT[kb + q * 4 + 1][j] = v.y;
                    WsT[kb + q * 4 + 2][j] = v.z; WsT[kb + q * 4 + 3][j] = v.w;
                }
            }
            __syncthreads();
#pragma unroll 4
            for (int k = 0; k < 64; ++k) {
                float4 a = *(float4*)&KsT[k][ti * 4];
                float4 b = *(float4*)&WsT[k][tj * 4];
                float av[4] = {a.x, a.y, a.z, a.w};
                float bv[4] = {b.x, b.y, b.z, b.w};
#pragma unroll
                for (int di = 0; di < 4; ++di)
#pragma unroll
                    for (int dj = 0; dj < 4; ++dj)
                        hacc[di][dj] += av[di] * bv[dj];
            }
        }
        __syncthreads();
#pragma unroll
        for (int di = 0; di < 4; ++di)
#pragma unroll
            for (int dj = 0; dj < 4; ++dj) {
                float h = hacc[di][dj] + cb1[j0 + tj * 4 + dj];
                Hs2[ti * 4 + di][tj * 4 + dj] = fmaxf(h, 0.f);
            }
        // stage cw2 j-slice
        {
            const int c  = tid >> 3;
            const int jq = (tid & 7) * 8;
            *(float4*)&W2s[c][jq]     = *(const float4*)&cw2[(size_t)c * HHALF + j0 + jq];
            *(float4*)&W2s[c][jq + 4] = *(const float4*)&cw2[(size_t)c * HHALF + j0 + jq + 4];
        }
        __syncthreads();
        float sacc[8];
#pragma unroll
        for (int q = 0; q < 8; ++q) sacc[q] = 0.f;
        for (int j = 0; j < 64; ++j) {
            float h = Hs2[si][j];
#pragma unroll
            for (int q = 0; q < 8; ++q) sacc[q] += h * W2s[sc0 + q][j];
        }
        if (si < M) {
#pragma unroll
            for (int q = 0; q < 8; ++q)
                atomicAdd(&scoresR[(size_t)(rc * 64 + si) * NC + sc0 + q], sacc[q]);
        }
        __syncthreads();
    }
}

// Kernel 1c: overwrite idx for refined rows
__global__ __launch_bounds__(256) void k_refine_fix(
    const int* __restrict__ rcnt, const int* __restrict__ rrows,
    const float* __restrict__ scoresR, const float* __restrict__ cb2,
    int* __restrict__ idx)
{
    const int cnt = min(*rcnt, REFINE_CAP);
    const int t = blockIdx.x * 256 + threadIdx.x;
    if (t >= cnt) return;
    float best = -3.4e38f;
    int bi = 0;
    for (int c = 0; c < NC; ++c) {
        float v = scoresR[(size_t)t * NC + c] + cb2[c];
        if (v > best) { best = v; bi = c; }
    }
    idx[rrows[t]] = bi;
}

// Kernel 2: counts histogram
__global__ __launch_bounds__(256) void k_counts(const int* __restrict__ idx,
                                                float* __restrict__ counts)
{
    __shared__ int hist[NC];
    if (threadIdx.x < NC) hist[threadIdx.x] = 0;
    __syncthreads();
    const int i = blockIdx.x * 256 + threadIdx.x;
    atomicAdd(&hist[idx[i]], 1);
    __syncthreads();
    if (threadIdx.x < NC)
        atomicAdd(&counts[threadIdx.x], (float)hist[threadIdx.x]);
}

// Kernel 3: segment sums of K and V into kcent/vcent (pre-zeroed).
__global__ __launch_bounds__(256) void k_segsum(
    const float* __restrict__ K, const float* __restrict__ V,
    const int* __restrict__ idx, float* __restrict__ ksum,
    float* __restrict__ vsum)
{
    __shared__ float ks_l[NC][256];
    __shared__ float vs_l[NC][256];
    const int hs  = blockIdx.x & 7;
    const int rc  = blockIdx.x >> 3;
    const int col = threadIdx.x;
    const int hb  = hs * 256;
#pragma unroll
    for (int c = 0; c < NC; ++c) { ks_l[c][col] = 0.f; vs_l[c][col] = 0.f; }
    __syncthreads();
    const int r0 = rc * 512;
    for (int r = r0; r < r0 + 512; ++r) {
        const int c = idx[r];
        atomicAdd(&ks_l[c][col], K[(size_t)r * HDIM + hb + col]);
        atomicAdd(&vs_l[c][col], V[(size_t)r * HDIM + hb + col]);
    }
    __syncthreads();
    for (int c = 0; c < NC; ++c) {
        atomicAdd(&ksum[c * HDIM + hb + col], ks_l[c][col]);
        atomicAdd(&vsum[c * HDIM + hb + col], vs_l[c][col]);
    }
}

// Kernel 4a: sums -> means (in place)
__global__ __launch_bounds__(256) void k_final1(float* __restrict__ kc,
                                                float* __restrict__ vc,
                                                const float* __restrict__ counts)
{
    const int e = blockIdx.x * 256 + threadIdx.x;
    const int c = e >> 11;
    const float denom = fmaxf(counts[c], 1.f);
    kc[e] /= denom;
    vc[e] /= denom;
}

// Kernel 4b: reseed empty centroids
__global__ __launch_bounds__(256) void k_final2(
    float* __restrict__ kc, float* __restrict__ vc,
    const float* __restrict__ counts, const float* __restrict__ nk,
    const float* __restrict__ nv)
{
    const int e = blockIdx.x * 256 + threadIdx.x;
    const int c = e >> 11;
    const int h = e & 2047;
    if (counts[c] == 0.f) {
        int src = 0;
        float best = counts[0];
        for (int j = 1; j < NC; ++j) {
            float v = counts[j];
            if (v > best) { best = v; src = j; }
        }
        kc[e] = kc[src * HDIM + h] + 0.1f * nk[e];
        vc[e] = vc[src * HDIM + h] + 0.1f * nv[e];
    }
}

// Kernel 5: one MLP layer over the 32 centroids
__global__ __launch_bounds__(256) void k_mlp(
    const float* __restrict__ Xk, const float* __restrict__ Xv,
    const float* __restrict__ W, const float* __restrict__ bias,
    float* __restrict__ Ok, float* __restrict__ Ov, int relu)
{
    __shared__ float Xs[32][65];
    __shared__ float Wt[64][65];
    const float* X = blockIdx.y ? Xv : Xk;
    float* O       = blockIdx.y ? Ov : Ok;
    const int tid   = threadIdx.x;
    const int jbase = blockIdx.x * 64;
    const int ti = tid & 7;
    const int tj = tid >> 3;
    float acc[4][2];
#pragma unroll
    for (int a = 0; a < 4; ++a) { acc[a][0] = 0.f; acc[a][1] = 0.f; }

    for (int kt = 0; kt < 32; ++kt) {
        const int k0 = kt * 64;
        __syncthreads();
        {
            const int f4 = tid & 15;
            const int r  = tid >> 4;
#pragma unroll
            for (int rr = 0; rr < 2; ++rr) {
                const int row = r + rr * 16;
                float4 xv = *(const float4*)&X[(size_t)row * HDIM + k0 + f4 * 4];
                Xs[row][f4 * 4 + 0] = xv.x; Xs[row][f4 * 4 + 1] = xv.y;
                Xs[row][f4 * 4 + 2] = xv.z; Xs[row][f4 * 4 + 3] = xv.w;
            }
#pragma unroll
            for (int rr = 0; rr < 4; ++rr) {
                const int row = r + rr * 16;
                float4 wv = *(const float4*)&W[(size_t)(jbase + row) * HDIM + k0 + f4 * 4];
                Wt[row][f4 * 4 + 0] = wv.x; Wt[row][f4 * 4 + 1] = wv.y;
                Wt[row][f4 * 4 + 2] = wv.z; Wt[row][f4 * 4 + 3] = wv.w;
            }
        }
        __syncthreads();
#pragma unroll 8
        for (int k = 0; k < 64; ++k) {
            float a[4], b[2];
#pragma unroll
            for (int d = 0; d < 4; ++d) a[d] = Xs[ti * 4 + d][k];
#pragma unroll
            for (int d = 0; d < 2; ++d) b[d] = Wt[tj * 2 + d][k];
#pragma unroll
            for (int d = 0; d < 4; ++d)
#pragma unroll
                for (int e2 = 0; e2 < 2; ++e2)
                    acc[d][e2] += a[d] * b[e2];
        }
    }
#pragma unroll
    for (int d = 0; d < 4; ++d)
#pragma unroll
        for (int e2 = 0; e2 < 2; ++e2) {
            const int i = ti * 4 + d;
            const int j = jbase + tj * 2 + e2;
            float v = acc[d][e2] + bias[j];
            if (relu) v = fmaxf(v, 0.f);
            O[(size_t)i * HDIM + j] = v;
        }
}

// Kernel 6: output assembly
__global__ __launch_bounds__(256) void k_out(
    const float* __restrict__ K, const float* __restrict__ V,
    const float* __restrict__ imp, const int* __restrict__ idx,
    const float* __restrict__ tck, const float* __restrict__ tcv,
    float* __restrict__ ok, float* __restrict__ ov)
{
    const size_t total = (size_t)NROWS * (HDIM / 4);
    for (size_t e = (size_t)blockIdx.x * 256 + threadIdx.x; e < total;
         e += (size_t)gridDim.x * 256) {
        const int r = (int)(e >> 9);
        const int q = (int)(e & 511);
        const bool pass = imp[r] > 0.1f;
        const int c = idx[r];
        const float4* sk = pass ? (const float4*)&K[(size_t)r * HDIM]
                                : (const float4*)&tck[(size_t)c * HDIM];
        const float4* sv = pass ? (const float4*)&V[(size_t)r * HDIM]
                                : (const float4*)&tcv[(size_t)c * HDIM];
        ((float4*)ok)[e] = sk[q];
        ((float4*)ov)[e] = sv[q];
    }
}

extern "C" void kernel_launch(void* const* d_in, const int* in_sizes, int n_in,
                              void* d_out, int out_size, void* d_ws,
                              size_t ws_size, hipStream_t stream)
{
    (void)in_sizes; (void)n_in; (void)out_size; (void)ws_size;
    const float* keys   = (const float*)d_in[0];
    const float* values = (const float*)d_in[1];
    const float* imp    = (const float*)d_in[2];
    const float* cw1    = (const float*)d_in[3];
    const float* cb1    = (const float*)d_in[4];
    const float* cw2    = (const float*)d_in[5];
    const float* cb2    = (const float*)d_in[6];
    const float* tw1    = (const float*)d_in[7];
    const float* tb1    = (const float*)d_in[8];
    const float* tw2    = (const float*)d_in[9];
    const float* tb2    = (const float*)d_in[10];
    const float* nk     = (const float*)d_in[11];
    const float* nv     = (const float*)d_in[12];

    char* ws = (char*)d_ws;
    int*   idx    = (int*)ws;
    float* counts = (float*)(ws + (64 << 10));
    float* kcent  = (float*)(ws + (128 << 10));
    float* vcent  = (float*)(ws + (384 << 10));
    float* hk     = (float*)(ws + (640 << 10));
    float* hv     = (float*)(ws + (896 << 10));
    float* tck    = (float*)(ws + (1152 << 10));
    float* tcv    = (float*)(ws + (1408 << 10));
    const size_t RC_OFF = (size_t)1664 << 10;
    int*   rcnt    = (int*)(ws + RC_OFF);
    int*   rrows   = (int*)(ws + RC_OFF + 4096);
    float* scoresR = (float*)(ws + RC_OFF + 4096 + 8192);
    float* ok = (float*)d_out;
    float* ov = ok + (size_t)NROWS * HDIM;

    hipMemsetAsync(ws + (64 << 10), 0, (640 - 64) << 10, stream);
    hipMemsetAsync(ws + RC_OFF, 0, 4096 + 8192 + (REFINE_CAP * NC * 4), stream);

    k_scores_mfma<<<NROWS / 64, 256, 0, stream>>>(keys, cw1, cb1, cw2, cb2,
                                                  idx, rcnt, rrows);
    k_refine_gemm<<<128, 256, 0, stream>>>(keys, cw1, cb1, cw2, rcnt, rrows, scoresR);
    k_refine_fix<<<REFINE_CAP / 256, 256, 0, stream>>>(rcnt, rrows, scoresR, cb2, idx);
    k_counts<<<NROWS / 256, 256, 0, stream>>>(idx, counts);
    k_segsum<<<256, 256, 0, stream>>>(keys, values, idx, kcent, vcent);
    k_final1<<<(NC * HDIM) / 256, 256, 0, stream>>>(kcent, vcent, counts);
    k_final2<<<(NC * HDIM) / 256, 256, 0, stream>>>(kcent, vcent, counts, nk, nv);
    k_mlp<<<dim3(HDIM / 64, 2), 256, 0, stream>>>(kcent, vcent, tw1, tb1, hk, hv, 1);
    k_mlp<<<dim3(HDIM / 64, 2), 256, 0, stream>>>(hk, hv, tw2, tb2, tck, tcv, 0);
    k_out<<<2048, 256, 0, stream>>>(keys, values, imp, idx, tck, tcv, ok, ov);
}

// Round 3
// 1191.840 us; speedup vs baseline: 2.3001x; 1.2187x over previous
//
#include <hip/hip_runtime.h>
#include <hip/hip_bf16.h>

#define NROWS 16384
#define HDIM  2048
#define HHALF 1024
#define NC    32
#define REFINE_TH 0.002f
#define REFINE_CAP 2048

typedef __attribute__((ext_vector_type(8)))  short  short8;
typedef __attribute__((ext_vector_type(16))) float  f32x16;

typedef __attribute__((address_space(3))) void lds_void;
typedef const __attribute__((address_space(1))) void gbl_void;

static __device__ __forceinline__ short f2bf(float f) {
    __hip_bfloat16 h = __float2bfloat16(f);
    return *(short*)&h;
}
static __device__ __forceinline__ float bf2f(short s) {
    union { unsigned int i; float f; } v;
    v.i = ((unsigned int)(unsigned short)s) << 16;
    return v.f;
}
static __device__ __forceinline__ void gload16(const void* g, void* l) {
    __builtin_amdgcn_global_load_lds((gbl_void*)g, (lds_void*)l, 16, 0, 0);
}

// ---------------------------------------------------------------------------
// ws (small): [0,64K) idx | [64K,+128) counts | [128K,384K) kcent |
// [384K,640K) vcent | [640K,896K) hk | [896K,1152K) hv | [1152K,1408K) tck |
// [1408K,1664K) tcv | [1664K,+4) rcnt | +4K rrows[2048] | +12K scoresR[2048*32]
//
// d_out (256MB) doubles as big scratch until k_out overwrites it:
// [0,64M) khi | [64M,128M) klo | [128M,160M) hidH | [160M,192M) hidL |
// [192M,196M) w1hi | [196M,200M) w1lo | [200M,+64K) w2hi | +64K w2lo |
// [201M,+2M) scoresAll.  All consumed before k_out runs.
// ---------------------------------------------------------------------------

// fp32 -> (bf16 hi, bf16 lo) split, 8 elems/thread, grid-stride
__global__ __launch_bounds__(256) void k_split(const float* __restrict__ src,
                                               short* __restrict__ hi,
                                               short* __restrict__ lo, int n8)
{
    const int stride = gridDim.x * 256;
    for (int i = blockIdx.x * 256 + threadIdx.x; i < n8; i += stride) {
        float4 a = ((const float4*)src)[(size_t)i * 2];
        float4 b = ((const float4*)src)[(size_t)i * 2 + 1];
        float f[8] = {a.x, a.y, a.z, a.w, b.x, b.y, b.z, b.w};
        short h[8], l[8];
#pragma unroll
        for (int e = 0; e < 8; ++e) {
            h[e] = f2bf(f[e]);
            l[e] = f2bf(f[e] - bf2f(h[e]));
        }
        *(short8*)&hi[(size_t)i * 8] = *(short8*)h;
        *(short8*)&lo[(size_t)i * 8] = *(short8*)l;
    }
}

// GEMM1: hidden[16384,1024] = relu(K @ w1^T + b1), 3-split bf16 MFMA.
// 128x128 tile, BK=64, 4 waves (2x2), each wave 2x2 of 32x32x16 tiles.
// LDS 64KB -> 2 blocks/CU. global_load_lds width-16 staging (linear LDS).
// Block remap: xcd=d&7, jb outer -> w1 panel L2-resident per XCD.
__global__ __launch_bounds__(256) void k_gemm1(
    const short* __restrict__ khi, const short* __restrict__ klo,
    const short* __restrict__ w1hi, const short* __restrict__ w1lo,
    const float* __restrict__ cb1, short* __restrict__ hidH,
    short* __restrict__ hidL)
{
    __shared__ alignas(16) short Ah[128 * 64];
    __shared__ alignas(16) short Al[128 * 64];
    __shared__ alignas(16) short Bh[128 * 64];
    __shared__ alignas(16) short Bl[128 * 64];

    const int tid = threadIdx.x;
    const int w = tid >> 6, lane = tid & 63;
    const int wr = w & 1, wc = w >> 1;
    const int l31 = lane & 31, lq5 = lane >> 5;

    const int d = blockIdx.x;
    const int xcd = d & 7, t = d >> 3;
    const int jb = t >> 4;                  // 0..7  (col panel, outer per XCD)
    const int rb = ((t & 15) << 3) | xcd;   // 0..127 (row panel)
    const int row0 = rb * 128, col0 = jb * 128;

    f32x16 acc[2][2] = {};

    for (int kt = 0; kt < 32; ++kt) {
        const int k0 = kt * 64;
        __syncthreads();
#pragma unroll
        for (int q = 0; q < 4; ++q) {
            const int c = w * 4 + q;                 // 1KB chunk id (0..15)
            const int r = c * 8 + (lane >> 3);       // tile row (128B rows)
            const size_t ga = ((size_t)(row0 + r) * HDIM + k0) * 2 + (lane & 7) * 16;
            const size_t gb = ((size_t)(col0 + r) * HDIM + k0) * 2 + (lane & 7) * 16;
            gload16((const char*)khi + ga, &Ah[c * 512]);
            gload16((const char*)klo + ga, &Al[c * 512]);
            gload16((const char*)w1hi + gb, &Bh[c * 512]);
            gload16((const char*)w1lo + gb, &Bl[c * 512]);
        }
        __syncthreads();
#pragma unroll
        for (int ks = 0; ks < 4; ++ks) {
            const int ko = ks * 16 + lq5 * 8;
            short8 aH[2], aL[2], bH[2], bL[2];
#pragma unroll
            for (int m = 0; m < 2; ++m) {
                const int rr = wr * 64 + m * 32 + l31;
                aH[m] = *(const short8*)&Ah[rr * 64 + ko];
                aL[m] = *(const short8*)&Al[rr * 64 + ko];
            }
#pragma unroll
            for (int n = 0; n < 2; ++n) {
                const int cc = wc * 64 + n * 32 + l31;
                bH[n] = *(const short8*)&Bh[cc * 64 + ko];
                bL[n] = *(const short8*)&Bl[cc * 64 + ko];
            }
#pragma unroll
            for (int m = 0; m < 2; ++m)
#pragma unroll
                for (int n = 0; n < 2; ++n) {
                    acc[m][n] = __builtin_amdgcn_mfma_f32_32x32x16_bf16(aH[m], bH[n], acc[m][n], 0, 0, 0);
                    acc[m][n] = __builtin_amdgcn_mfma_f32_32x32x16_bf16(aH[m], bL[n], acc[m][n], 0, 0, 0);
                    acc[m][n] = __builtin_amdgcn_mfma_f32_32x32x16_bf16(aL[m], bH[n], acc[m][n], 0, 0, 0);
                }
        }
    }
    // epilogue: bias + relu, store hidden as hi/lo bf16
#pragma unroll
    for (int n = 0; n < 2; ++n) {
        const int col = col0 + wc * 64 + n * 32 + l31;
        const float bias = cb1[col];
#pragma unroll
        for (int m = 0; m < 2; ++m) {
#pragma unroll
            for (int r = 0; r < 16; ++r) {
                const int row = row0 + wr * 64 + m * 32 + (r & 3) + 8 * (r >> 2) + 4 * lq5;
                float h = acc[m][n][r] + bias;
                h = fmaxf(h, 0.f);
                const short hh = f2bf(h);
                hidH[(size_t)row * HHALF + col] = hh;
                hidL[(size_t)row * HHALF + col] = f2bf(h - bf2f(hh));
            }
        }
    }
}

// GEMM2: scoresAll[16384,32] = hidden @ w2^T (3-split bf16 MFMA).
// 128 rows/block, 4 waves x 32 rows, k=1024 in 8 tiles of 128. LDS 80KB.
__global__ __launch_bounds__(256) void k_gemm2(
    const short* __restrict__ hidH, const short* __restrict__ hidL,
    const short* __restrict__ w2hi, const short* __restrict__ w2lo,
    float* __restrict__ scoresAll)
{
    __shared__ alignas(16) short HsH[128 * 128];
    __shared__ alignas(16) short HsL[128 * 128];
    __shared__ alignas(16) short W2h[32 * 128];
    __shared__ alignas(16) short W2l[32 * 128];

    const int tid = threadIdx.x;
    const int w = tid >> 6, lane = tid & 63;
    const int l31 = lane & 31, lq5 = lane >> 5;
    const int row0 = blockIdx.x * 128;

    f32x16 sacc = {};

    for (int jt = 0; jt < 8; ++jt) {
        const int kk0 = jt * 128;
        __syncthreads();
#pragma unroll
        for (int q = 0; q < 8; ++q) {
            const int c = w * 8 + q;                 // 1KB chunk (4 rows x 256B)
            const int r = c * 4 + (lane >> 4);
            const size_t g = ((size_t)(row0 + r) * HHALF + kk0) * 2 + (lane & 15) * 16;
            gload16((const char*)hidH + g, &HsH[c * 512]);
            gload16((const char*)hidL + g, &HsL[c * 512]);
        }
#pragma unroll
        for (int q = 0; q < 2; ++q) {
            const int c = w * 2 + q;
            const int r = c * 4 + (lane >> 4);
            const size_t g = ((size_t)r * HHALF + kk0) * 2 + (lane & 15) * 16;
            gload16((const char*)w2hi + g, &W2h[c * 512]);
            gload16((const char*)w2lo + g, &W2l[c * 512]);
        }
        __syncthreads();
#pragma unroll
        for (int ks = 0; ks < 8; ++ks) {
            const int ko = ks * 16 + lq5 * 8;
            short8 aH = *(const short8*)&HsH[(w * 32 + l31) * 128 + ko];
            short8 aL = *(const short8*)&HsL[(w * 32 + l31) * 128 + ko];
            short8 bH = *(const short8*)&W2h[l31 * 128 + ko];
            short8 bL = *(const short8*)&W2l[l31 * 128 + ko];
            sacc = __builtin_amdgcn_mfma_f32_32x32x16_bf16(aH, bH, sacc, 0, 0, 0);
            sacc = __builtin_amdgcn_mfma_f32_32x32x16_bf16(aH, bL, sacc, 0, 0, 0);
            sacc = __builtin_amdgcn_mfma_f32_32x32x16_bf16(aL, bH, sacc, 0, 0, 0);
        }
    }
#pragma unroll
    for (int r = 0; r < 16; ++r) {
        const int row = row0 + w * 32 + (r & 3) + 8 * (r >> 2) + 4 * lq5;
        scoresAll[(size_t)row * NC + l31] = sacc[r];
    }
}

// argmax + low-margin flagging (one thread per row)
__global__ __launch_bounds__(256) void k_argmax(
    const float* __restrict__ scoresAll, const float* __restrict__ cb2,
    int* __restrict__ idx, int* __restrict__ rcnt, int* __restrict__ rrows)
{
    const int row = blockIdx.x * 256 + threadIdx.x;
    const float4* s4 = (const float4*)&scoresAll[(size_t)row * NC];
    float best = -3.4e38f, second = -3.4e38f;
    int bi = 0;
#pragma unroll
    for (int q = 0; q < 8; ++q) {
        float4 v = s4[q];
        float vv[4] = {v.x, v.y, v.z, v.w};
#pragma unroll
        for (int e = 0; e < 4; ++e) {
            const int c = q * 4 + e;
            const float s = vv[e] + cb2[c];
            if (s > best) { second = best; best = s; bi = c; }
            else if (s > second) second = s;
        }
    }
    idx[row] = bi;
    if (best - second < REFINE_TH) {
        int slot = atomicAdd(rcnt, 1);
        if (slot < REFINE_CAP) rrows[slot] = row;
    }
}

// exact fp32 recompute of scores for flagged rows (expected ~0 rows now)
__global__ __launch_bounds__(256) void k_refine_gemm(
    const float* __restrict__ K, const float* __restrict__ cw1,
    const float* __restrict__ cb1, const float* __restrict__ cw2,
    const int* __restrict__ rcnt, const int* __restrict__ rrows,
    float* __restrict__ scoresR)
{
    const int cnt = min(*rcnt, REFINE_CAP);
    if (cnt == 0) return;
    const int units = ((cnt + 63) >> 6) * 16;
    __shared__ float KsT[64][68];
    __shared__ float WsT[64][68];
    __shared__ float Hs2[64][68];
    __shared__ float W2s[NC][68];

    const int tid = threadIdx.x;
    const int ti = tid & 15, tj = tid >> 4;
    const int si = tid & 63, sc0 = (tid >> 6) * 8;

    for (int u = blockIdx.x; u < units; u += gridDim.x) {
        const int rc = u >> 4, jt = u & 15, j0 = jt * 64;
        const int M = min(cnt - rc * 64, 64);

        float hacc[4][4];
#pragma unroll
        for (int a = 0; a < 4; ++a)
#pragma unroll
            for (int b = 0; b < 4; ++b) hacc[a][b] = 0.f;

        for (int kt = 0; kt < 32; ++kt) {
            const int k0 = kt * 64;
            __syncthreads();
            {
                const int r  = tid >> 2;
                const int kb = (tid & 3) * 16;
                const int grow = rrows[rc * 64 + min(r, M - 1)];
#pragma unroll
                for (int q = 0; q < 4; ++q) {
                    float4 v = *(const float4*)&K[(size_t)grow * HDIM + k0 + kb + q * 4];
                    KsT[kb + q * 4 + 0][r] = v.x; KsT[kb + q * 4 + 1][r] = v.y;
                    KsT[kb + q * 4 + 2][r] = v.z; KsT[kb + q * 4 + 3][r] = v.w;
                }
                const int j = tid >> 2;
#pragma unroll
                for (int q = 0; q < 4; ++q) {
                    float4 v = *(const float4*)&cw1[(size_t)(j0 + j) * HDIM + k0 + kb + q * 4];
                    WsT[kb + q * 4 + 0][j] = v.x; WsT[kb + q * 4 + 1][j] = v.y;
                    WsT[kb + q * 4 + 2][j] = v.z; WsT[kb + q * 4 + 3][j] = v.w;
                }
            }
            __syncthreads();
#pragma unroll 4
            for (int k = 0; k < 64; ++k) {
                float4 a = *(float4*)&KsT[k][ti * 4];
                float4 b = *(float4*)&WsT[k][tj * 4];
                float av[4] = {a.x, a.y, a.z, a.w};
                float bv[4] = {b.x, b.y, b.z, b.w};
#pragma unroll
                for (int di = 0; di < 4; ++di)
#pragma unroll
                    for (int dj = 0; dj < 4; ++dj)
                        hacc[di][dj] += av[di] * bv[dj];
            }
        }
        __syncthreads();
#pragma unroll
        for (int di = 0; di < 4; ++di)
#pragma unroll
            for (int dj = 0; dj < 4; ++dj) {
                float h = hacc[di][dj] + cb1[j0 + tj * 4 + dj];
                Hs2[ti * 4 + di][tj * 4 + dj] = fmaxf(h, 0.f);
            }
        {
            const int c  = tid >> 3;
            const int jq = (tid & 7) * 8;
            *(float4*)&W2s[c][jq]     = *(const float4*)&cw2[(size_t)c * HHALF + j0 + jq];
            *(float4*)&W2s[c][jq + 4] = *(const float4*)&cw2[(size_t)c * HHALF + j0 + jq + 4];
        }
        __syncthreads();
        float sacc[8];
#pragma unroll
        for (int q = 0; q < 8; ++q) sacc[q] = 0.f;
        for (int j = 0; j < 64; ++j) {
            float h = Hs2[si][j];
#pragma unroll
            for (int q = 0; q < 8; ++q) sacc[q] += h * W2s[sc0 + q][j];
        }
        if (si < M) {
#pragma unroll
            for (int q = 0; q < 8; ++q)
                atomicAdd(&scoresR[(size_t)(rc * 64 + si) * NC + sc0 + q], sacc[q]);
        }
        __syncthreads();
    }
}

__global__ __launch_bounds__(256) void k_refine_fix(
    const int* __restrict__ rcnt, const int* __restrict__ rrows,
    const float* __restrict__ scoresR, const float* __restrict__ cb2,
    int* __restrict__ idx)
{
    const int cnt = min(*rcnt, REFINE_CAP);
    const int t = blockIdx.x * 256 + threadIdx.x;
    if (t >= cnt) return;
    float best = -3.4e38f;
    int bi = 0;
    for (int c = 0; c < NC; ++c) {
        float v = scoresR[(size_t)t * NC + c] + cb2[c];
        if (v > best) { best = v; bi = c; }
    }
    idx[rrows[t]] = bi;
}

__global__ __launch_bounds__(256) void k_counts(const int* __restrict__ idx,
                                                float* __restrict__ counts)
{
    __shared__ int hist[NC];
    if (threadIdx.x < NC) hist[threadIdx.x] = 0;
    __syncthreads();
    const int i = blockIdx.x * 256 + threadIdx.x;
    atomicAdd(&hist[idx[i]], 1);
    __syncthreads();
    if (threadIdx.x < NC)
        atomicAdd(&counts[threadIdx.x], (float)hist[threadIdx.x]);
}

__global__ __launch_bounds__(256) void k_segsum(
    const float* __restrict__ K, const float* __restrict__ V,
    const int* __restrict__ idx, float* __restrict__ ksum,
    float* __restrict__ vsum)
{
    __shared__ float ks_l[NC][256];
    __shared__ float vs_l[NC][256];
    const int hs  = blockIdx.x & 7;
    const int rc  = blockIdx.x >> 3;
    const int col = threadIdx.x;
    const int hb  = hs * 256;
#pragma unroll
    for (int c = 0; c < NC; ++c) { ks_l[c][col] = 0.f; vs_l[c][col] = 0.f; }
    __syncthreads();
    const int r0 = rc * 512;
    for (int r = r0; r < r0 + 512; ++r) {
        const int c = idx[r];
        atomicAdd(&ks_l[c][col], K[(size_t)r * HDIM + hb + col]);
        atomicAdd(&vs_l[c][col], V[(size_t)r * HDIM + hb + col]);
    }
    __syncthreads();
    for (int c = 0; c < NC; ++c) {
        atomicAdd(&ksum[c * HDIM + hb + col], ks_l[c][col]);
        atomicAdd(&vsum[c * HDIM + hb + col], vs_l[c][col]);
    }
}

__global__ __launch_bounds__(256) void k_final1(float* __restrict__ kc,
                                                float* __restrict__ vc,
                                                const float* __restrict__ counts)
{
    const int e = blockIdx.x * 256 + threadIdx.x;
    const int c = e >> 11;
    const float denom = fmaxf(counts[c], 1.f);
    kc[e] /= denom;
    vc[e] /= denom;
}

__global__ __launch_bounds__(256) void k_final2(
    float* __restrict__ kc, float* __restrict__ vc,
    const float* __restrict__ counts, const float* __restrict__ nk,
    const float* __restrict__ nv)
{
    const int e = blockIdx.x * 256 + threadIdx.x;
    const int c = e >> 11;
    const int h = e & 2047;
    if (counts[c] == 0.f) {
        int src = 0;
        float best = counts[0];
        for (int j = 1; j < NC; ++j) {
            float v = counts[j];
            if (v > best) { best = v; src = j; }
        }
        kc[e] = kc[src * HDIM + h] + 0.1f * nk[e];
        vc[e] = vc[src * HDIM + h] + 0.1f * nv[e];
    }
}

__global__ __launch_bounds__(256) void k_mlp(
    const float* __restrict__ Xk, const float* __restrict__ Xv,
    const float* __restrict__ W, const float* __restrict__ bias,
    float* __restrict__ Ok, float* __restrict__ Ov, int relu)
{
    __shared__ float Xs[32][65];
    __shared__ float Wt[64][65];
    const float* X = blockIdx.y ? Xv : Xk;
    float* O       = blockIdx.y ? Ov : Ok;
    const int tid   = threadIdx.x;
    const int jbase = blockIdx.x * 64;
    const int ti = tid & 7;
    const int tj = tid >> 3;
    float acc[4][2];
#pragma unroll
    for (int a = 0; a < 4; ++a) { acc[a][0] = 0.f; acc[a][1] = 0.f; }

    for (int kt = 0; kt < 32; ++kt) {
        const int k0 = kt * 64;
        __syncthreads();
        {
            const int f4 = tid & 15;
            const int r  = tid >> 4;
#pragma unroll
            for (int rr = 0; rr < 2; ++rr) {
                const int row = r + rr * 16;
                float4 xv = *(const float4*)&X[(size_t)row * HDIM + k0 + f4 * 4];
                Xs[row][f4 * 4 + 0] = xv.x; Xs[row][f4 * 4 + 1] = xv.y;
                Xs[row][f4 * 4 + 2] = xv.z; Xs[row][f4 * 4 + 3] = xv.w;
            }
#pragma unroll
            for (int rr = 0; rr < 4; ++rr) {
                const int row = r + rr * 16;
                float4 wv = *(const float4*)&W[(size_t)(jbase + row) * HDIM + k0 + f4 * 4];
                Wt[row][f4 * 4 + 0] = wv.x; Wt[row][f4 * 4 + 1] = wv.y;
                Wt[row][f4 * 4 + 2] = wv.z; Wt[row][f4 * 4 + 3] = wv.w;
            }
        }
        __syncthreads();
#pragma unroll 8
        for (int k = 0; k < 64; ++k) {
            float a[4], b[2];
#pragma unroll
            for (int d = 0; d < 4; ++d) a[d] = Xs[ti * 4 + d][k];
#pragma unroll
            for (int d = 0; d < 2; ++d) b[d] = Wt[tj * 2 + d][k];
#pragma unroll
            for (int d = 0; d < 4; ++d)
#pragma unroll
                for (int e2 = 0; e2 < 2; ++e2)
                    acc[d][e2] += a[d] * b[e2];
        }
    }
#pragma unroll
    for (int d = 0; d < 4; ++d)
#pragma unroll
        for (int e2 = 0; e2 < 2; ++e2) {
            const int i = ti * 4 + d;
            const int j = jbase + tj * 2 + e2;
            float v = acc[d][e2] + bias[j];
            if (relu) v = fmaxf(v, 0.f);
            O[(size_t)i * HDIM + j] = v;
        }
}

__global__ __launch_bounds__(256) void k_out(
    const float* __restrict__ K, const float* __restrict__ V,
    const float* __restrict__ imp, const int* __restrict__ idx,
    const float* __restrict__ tck, const float* __restrict__ tcv,
    float* __restrict__ ok, float* __restrict__ ov)
{
    const size_t total = (size_t)NROWS * (HDIM / 4);
    for (size_t e = (size_t)blockIdx.x * 256 + threadIdx.x; e < total;
         e += (size_t)gridDim.x * 256) {
        const int r = (int)(e >> 9);
        const int q = (int)(e & 511);
        const bool pass = imp[r] > 0.1f;
        const int c = idx[r];
        const float4* sk = pass ? (const float4*)&K[(size_t)r * HDIM]
                                : (const float4*)&tck[(size_t)c * HDIM];
        const float4* sv = pass ? (const float4*)&V[(size_t)r * HDIM]
                                : (const float4*)&tcv[(size_t)c * HDIM];
        ((float4*)ok)[e] = sk[q];
        ((float4*)ov)[e] = sv[q];
    }
}

extern "C" void kernel_launch(void* const* d_in, const int* in_sizes, int n_in,
                              void* d_out, int out_size, void* d_ws,
                              size_t ws_size, hipStream_t stream)
{
    (void)in_sizes; (void)n_in; (void)out_size; (void)ws_size;
    const float* keys   = (const float*)d_in[0];
    const float* values = (const float*)d_in[1];
    const float* imp    = (const float*)d_in[2];
    const float* cw1    = (const float*)d_in[3];
    const float* cb1    = (const float*)d_in[4];
    const float* cw2    = (const float*)d_in[5];
    const float* cb2    = (const float*)d_in[6];
    const float* tw1    = (const float*)d_in[7];
    const float* tb1    = (const float*)d_in[8];
    const float* tw2    = (const float*)d_in[9];
    const float* tb2    = (const float*)d_in[10];
    const float* nk     = (const float*)d_in[11];
    const float* nv     = (const float*)d_in[12];

    char* ws = (char*)d_ws;
    int*   idx    = (int*)ws;
    float* counts = (float*)(ws + (64 << 10));
    float* kcent  = (float*)(ws + (128 << 10));
    float* vcent  = (float*)(ws + (384 << 10));
    float* hk     = (float*)(ws + (640 << 10));
    float* hv     = (float*)(ws + (896 << 10));
    float* tck    = (float*)(ws + (1152 << 10));
    float* tcv    = (float*)(ws + (1408 << 10));
    const size_t RC_OFF = (size_t)1664 << 10;
    int*   rcnt    = (int*)(ws + RC_OFF);
    int*   rrows   = (int*)(ws + RC_OFF + 4096);
    float* scoresR = (float*)(ws + RC_OFF + 4096 + 8192);

    // big scratch lives in d_out until k_out overwrites it
    const size_t MB = (size_t)1 << 20;
    char* ob = (char*)d_out;
    short* khi  = (short*)(ob);
    short* klo  = (short*)(ob + 64 * MB);
    short* hidH = (short*)(ob + 128 * MB);
    short* hidL = (short*)(ob + 160 * MB);
    short* w1hi = (short*)(ob + 192 * MB);
    short* w1lo = (short*)(ob + 196 * MB);
    short* w2hi = (short*)(ob + 200 * MB);
    short* w2lo = (short*)(ob + 200 * MB + (64 << 10));
    float* scoresAll = (float*)(ob + 201 * MB);
    float* ok = (float*)d_out;
    float* ov = ok + (size_t)NROWS * HDIM;

    hipMemsetAsync(ws + (64 << 10), 0, (640 - 64) << 10, stream);
    hipMemsetAsync(ws + RC_OFF, 0, 4096 + 8192 + REFINE_CAP * NC * 4, stream);

    k_split<<<2048, 256, 0, stream>>>(keys, khi, klo, NROWS * HDIM / 8);
    k_split<<<512, 256, 0, stream>>>(cw1, w1hi, w1lo, HHALF * HDIM / 8);
    k_split<<<16, 256, 0, stream>>>(cw2, w2hi, w2lo, NC * HHALF / 8);
    k_gemm1<<<1024, 256, 0, stream>>>(khi, klo, w1hi, w1lo, cb1, hidH, hidL);
    k_gemm2<<<NROWS / 128, 256, 0, stream>>>(hidH, hidL, w2hi, w2lo, scoresAll);
    k_argmax<<<NROWS / 256, 256, 0, stream>>>(scoresAll, cb2, idx, rcnt, rrows);
    k_refine_gemm<<<128, 256, 0, stream>>>(keys, cw1, cb1, cw2, rcnt, rrows, scoresR);
    k_refine_fix<<<REFINE_CAP / 256, 256, 0, stream>>>(rcnt, rrows, scoresR, cb2, idx);
    k_counts<<<NROWS / 256, 256, 0, stream>>>(idx, counts);
    k_segsum<<<256, 256, 0, stream>>>(keys, values, idx, kcent, vcent);
    k_final1<<<(NC * HDIM) / 256, 256, 0, stream>>>(kcent, vcent, counts);
    k_final2<<<(NC * HDIM) / 256, 256, 0, stream>>>(kcent, vcent, counts, nk, nv);
    k_mlp<<<dim3(HDIM / 64, 2), 256, 0, stream>>>(kcent, vcent, tw1, tb1, hk, hv, 1);
    k_mlp<<<dim3(HDIM / 64, 2), 256, 0, stream>>>(hk, hv, tw2, tb2, tck, tcv, 0);
    k_out<<<2048, 256, 0, stream>>>(keys, values, imp, idx, tck, tcv, ok, ov);
}

// Round 4
// 1046.511 us; speedup vs baseline: 2.6195x; 1.1389x over previous
//
#include <hip/hip_runtime.h>
#include <hip/hip_bf16.h>

#define NROWS 16384
#define HDIM  2048
#define HHALF 1024
#define NC    32
#define REFINE_TH 0.002f
#define REFINE_CAP 2048

typedef __attribute__((ext_vector_type(8)))  short  short8;
typedef __attribute__((ext_vector_type(16))) float  f32x16;

typedef __attribute__((address_space(3))) void lds_void;
typedef const __attribute__((address_space(1))) void gbl_void;

static __device__ __forceinline__ short f2bf(float f) {
    __hip_bfloat16 h = __float2bfloat16(f);
    return *(short*)&h;
}
static __device__ __forceinline__ float bf2f(short s) {
    union { unsigned int i; float f; } v;
    v.i = ((unsigned int)(unsigned short)s) << 16;
    return v.f;
}
static __device__ __forceinline__ void gload16(const void* g, void* l) {
    __builtin_amdgcn_global_load_lds((gbl_void*)g, (lds_void*)l, 16, 0, 0);
}

// ---------------------------------------------------------------------------
// ws (small): [0,64K) idx | [64K,+128) counts | [128K,384K) kcent |
// [384K,640K) vcent | [640K,896K) hk | [896K,1152K) hv | [1152K,1408K) tck |
// [1408K,1664K) tcv | [1664K,+4) rcnt | +4K rrows[2048] | +12K scoresR[2048*32]
//
// d_out (256MB) doubles as big scratch until k_out overwrites it:
// [0,64M) khi | [64M,128M) klo | [128M,160M) hidH | [160M,192M) hidL |
// [192M,196M) w1hi | [196M,200M) w1lo | [200M,+64K) w2hi | +64K w2lo |
// [201M,+2M) scoresAll | [204M,+128) offsets | +128 cursor | +4K rowlist[16384]
// All consumed before k_out runs.
// ---------------------------------------------------------------------------

// fp32 -> (bf16 hi, bf16 lo) split, 8 elems/thread, grid-stride
__global__ __launch_bounds__(256) void k_split(const float* __restrict__ src,
                                               short* __restrict__ hi,
                                               short* __restrict__ lo, int n8)
{
    const int stride = gridDim.x * 256;
    for (int i = blockIdx.x * 256 + threadIdx.x; i < n8; i += stride) {
        float4 a = ((const float4*)src)[(size_t)i * 2];
        float4 b = ((const float4*)src)[(size_t)i * 2 + 1];
        float f[8] = {a.x, a.y, a.z, a.w, b.x, b.y, b.z, b.w};
        short h[8], l[8];
#pragma unroll
        for (int e = 0; e < 8; ++e) {
            h[e] = f2bf(f[e]);
            l[e] = f2bf(f[e] - bf2f(h[e]));
        }
        *(short8*)&hi[(size_t)i * 8] = *(short8*)h;
        *(short8*)&lo[(size_t)i * 8] = *(short8*)l;
    }
}

// GEMM1: hidden[16384,1024] = relu(K @ w1^T + b1), 3-split bf16 MFMA.
__global__ __launch_bounds__(256) void k_gemm1(
    const short* __restrict__ khi, const short* __restrict__ klo,
    const short* __restrict__ w1hi, const short* __restrict__ w1lo,
    const float* __restrict__ cb1, short* __restrict__ hidH,
    short* __restrict__ hidL)
{
    __shared__ alignas(16) short Ah[128 * 64];
    __shared__ alignas(16) short Al[128 * 64];
    __shared__ alignas(16) short Bh[128 * 64];
    __shared__ alignas(16) short Bl[128 * 64];

    const int tid = threadIdx.x;
    const int w = tid >> 6, lane = tid & 63;
    const int wr = w & 1, wc = w >> 1;
    const int l31 = lane & 31, lq5 = lane >> 5;

    const int d = blockIdx.x;
    const int xcd = d & 7, t = d >> 3;
    const int jb = t >> 4;
    const int rb = ((t & 15) << 3) | xcd;
    const int row0 = rb * 128, col0 = jb * 128;

    f32x16 acc[2][2] = {};

    for (int kt = 0; kt < 32; ++kt) {
        const int k0 = kt * 64;
        __syncthreads();
#pragma unroll
        for (int q = 0; q < 4; ++q) {
            const int c = w * 4 + q;
            const int r = c * 8 + (lane >> 3);
            const size_t ga = ((size_t)(row0 + r) * HDIM + k0) * 2 + (lane & 7) * 16;
            const size_t gb = ((size_t)(col0 + r) * HDIM + k0) * 2 + (lane & 7) * 16;
            gload16((const char*)khi + ga, &Ah[c * 512]);
            gload16((const char*)klo + ga, &Al[c * 512]);
            gload16((const char*)w1hi + gb, &Bh[c * 512]);
            gload16((const char*)w1lo + gb, &Bl[c * 512]);
        }
        __syncthreads();
#pragma unroll
        for (int ks = 0; ks < 4; ++ks) {
            const int ko = ks * 16 + lq5 * 8;
            short8 aH[2], aL[2], bH[2], bL[2];
#pragma unroll
            for (int m = 0; m < 2; ++m) {
                const int rr = wr * 64 + m * 32 + l31;
                aH[m] = *(const short8*)&Ah[rr * 64 + ko];
                aL[m] = *(const short8*)&Al[rr * 64 + ko];
            }
#pragma unroll
            for (int n = 0; n < 2; ++n) {
                const int cc = wc * 64 + n * 32 + l31;
                bH[n] = *(const short8*)&Bh[cc * 64 + ko];
                bL[n] = *(const short8*)&Bl[cc * 64 + ko];
            }
#pragma unroll
            for (int m = 0; m < 2; ++m)
#pragma unroll
                for (int n = 0; n < 2; ++n) {
                    acc[m][n] = __builtin_amdgcn_mfma_f32_32x32x16_bf16(aH[m], bH[n], acc[m][n], 0, 0, 0);
                    acc[m][n] = __builtin_amdgcn_mfma_f32_32x32x16_bf16(aH[m], bL[n], acc[m][n], 0, 0, 0);
                    acc[m][n] = __builtin_amdgcn_mfma_f32_32x32x16_bf16(aL[m], bH[n], acc[m][n], 0, 0, 0);
                }
        }
    }
#pragma unroll
    for (int n = 0; n < 2; ++n) {
        const int col = col0 + wc * 64 + n * 32 + l31;
        const float bias = cb1[col];
#pragma unroll
        for (int m = 0; m < 2; ++m) {
#pragma unroll
            for (int r = 0; r < 16; ++r) {
                const int row = row0 + wr * 64 + m * 32 + (r & 3) + 8 * (r >> 2) + 4 * lq5;
                float h = acc[m][n][r] + bias;
                h = fmaxf(h, 0.f);
                const short hh = f2bf(h);
                hidH[(size_t)row * HHALF + col] = hh;
                hidL[(size_t)row * HHALF + col] = f2bf(h - bf2f(hh));
            }
        }
    }
}

// GEMM2: scoresAll[16384,32] = hidden @ w2^T (3-split bf16 MFMA).
__global__ __launch_bounds__(256) void k_gemm2(
    const short* __restrict__ hidH, const short* __restrict__ hidL,
    const short* __restrict__ w2hi, const short* __restrict__ w2lo,
    float* __restrict__ scoresAll)
{
    __shared__ alignas(16) short HsH[128 * 128];
    __shared__ alignas(16) short HsL[128 * 128];
    __shared__ alignas(16) short W2h[32 * 128];
    __shared__ alignas(16) short W2l[32 * 128];

    const int tid = threadIdx.x;
    const int w = tid >> 6, lane = tid & 63;
    const int l31 = lane & 31, lq5 = lane >> 5;
    const int row0 = blockIdx.x * 128;

    f32x16 sacc = {};

    for (int jt = 0; jt < 8; ++jt) {
        const int kk0 = jt * 128;
        __syncthreads();
#pragma unroll
        for (int q = 0; q < 8; ++q) {
            const int c = w * 8 + q;
            const int r = c * 4 + (lane >> 4);
            const size_t g = ((size_t)(row0 + r) * HHALF + kk0) * 2 + (lane & 15) * 16;
            gload16((const char*)hidH + g, &HsH[c * 512]);
            gload16((const char*)hidL + g, &HsL[c * 512]);
        }
#pragma unroll
        for (int q = 0; q < 2; ++q) {
            const int c = w * 2 + q;
            const int r = c * 4 + (lane >> 4);
            const size_t g = ((size_t)r * HHALF + kk0) * 2 + (lane & 15) * 16;
            gload16((const char*)w2hi + g, &W2h[c * 512]);
            gload16((const char*)w2lo + g, &W2l[c * 512]);
        }
        __syncthreads();
#pragma unroll
        for (int ks = 0; ks < 8; ++ks) {
            const int ko = ks * 16 + lq5 * 8;
            short8 aH = *(const short8*)&HsH[(w * 32 + l31) * 128 + ko];
            short8 aL = *(const short8*)&HsL[(w * 32 + l31) * 128 + ko];
            short8 bH = *(const short8*)&W2h[l31 * 128 + ko];
            short8 bL = *(const short8*)&W2l[l31 * 128 + ko];
            sacc = __builtin_amdgcn_mfma_f32_32x32x16_bf16(aH, bH, sacc, 0, 0, 0);
            sacc = __builtin_amdgcn_mfma_f32_32x32x16_bf16(aH, bL, sacc, 0, 0, 0);
            sacc = __builtin_amdgcn_mfma_f32_32x32x16_bf16(aL, bH, sacc, 0, 0, 0);
        }
    }
#pragma unroll
    for (int r = 0; r < 16; ++r) {
        const int row = row0 + w * 32 + (r & 3) + 8 * (r >> 2) + 4 * lq5;
        scoresAll[(size_t)row * NC + l31] = sacc[r];
    }
}

// argmax + low-margin flagging
__global__ __launch_bounds__(256) void k_argmax(
    const float* __restrict__ scoresAll, const float* __restrict__ cb2,
    int* __restrict__ idx, int* __restrict__ rcnt, int* __restrict__ rrows)
{
    const int row = blockIdx.x * 256 + threadIdx.x;
    const float4* s4 = (const float4*)&scoresAll[(size_t)row * NC];
    float best = -3.4e38f, second = -3.4e38f;
    int bi = 0;
#pragma unroll
    for (int q = 0; q < 8; ++q) {
        float4 v = s4[q];
        float vv[4] = {v.x, v.y, v.z, v.w};
#pragma unroll
        for (int e = 0; e < 4; ++e) {
            const int c = q * 4 + e;
            const float s = vv[e] + cb2[c];
            if (s > best) { second = best; best = s; bi = c; }
            else if (s > second) second = s;
        }
    }
    idx[row] = bi;
    if (best - second < REFINE_TH) {
        int slot = atomicAdd(rcnt, 1);
        if (slot < REFINE_CAP) rrows[slot] = row;
    }
}

// exact fp32 recompute of scores for flagged rows (expected ~0 rows)
__global__ __launch_bounds__(256) void k_refine_gemm(
    const float* __restrict__ K, const float* __restrict__ cw1,
    const float* __restrict__ cb1, const float* __restrict__ cw2,
    const int* __restrict__ rcnt, const int* __restrict__ rrows,
    float* __restrict__ scoresR)
{
    const int cnt = min(*rcnt, REFINE_CAP);
    if (cnt == 0) return;
    const int units = ((cnt + 63) >> 6) * 16;
    __shared__ float KsT[64][68];
    __shared__ float WsT[64][68];
    __shared__ float Hs2[64][68];
    __shared__ float W2s[NC][68];

    const int tid = threadIdx.x;
    const int ti = tid & 15, tj = tid >> 4;
    const int si = tid & 63, sc0 = (tid >> 6) * 8;

    for (int u = blockIdx.x; u < units; u += gridDim.x) {
        const int rc = u >> 4, jt = u & 15, j0 = jt * 64;
        const int M = min(cnt - rc * 64, 64);

        float hacc[4][4];
#pragma unroll
        for (int a = 0; a < 4; ++a)
#pragma unroll
            for (int b = 0; b < 4; ++b) hacc[a][b] = 0.f;

        for (int kt = 0; kt < 32; ++kt) {
            const int k0 = kt * 64;
            __syncthreads();
            {
                const int r  = tid >> 2;
                const int kb = (tid & 3) * 16;
                const int grow = rrows[rc * 64 + min(r, M - 1)];
#pragma unroll
                for (int q = 0; q < 4; ++q) {
                    float4 v = *(const float4*)&K[(size_t)grow * HDIM + k0 + kb + q * 4];
                    KsT[kb + q * 4 + 0][r] = v.x; KsT[kb + q * 4 + 1][r] = v.y;
                    KsT[kb + q * 4 + 2][r] = v.z; KsT[kb + q * 4 + 3][r] = v.w;
                }
                const int j = tid >> 2;
#pragma unroll
                for (int q = 0; q < 4; ++q) {
                    float4 v = *(const float4*)&cw1[(size_t)(j0 + j) * HDIM + k0 + kb + q * 4];
                    WsT[kb + q * 4 + 0][j] = v.x; WsT[kb + q * 4 + 1][j] = v.y;
                    WsT[kb + q * 4 + 2][j] = v.z; WsT[kb + q * 4 + 3][j] = v.w;
                }
            }
            __syncthreads();
#pragma unroll 4
            for (int k = 0; k < 64; ++k) {
                float4 a = *(float4*)&KsT[k][ti * 4];
                float4 b = *(float4*)&WsT[k][tj * 4];
                float av[4] = {a.x, a.y, a.z, a.w};
                float bv[4] = {b.x, b.y, b.z, b.w};
#pragma unroll
                for (int di = 0; di < 4; ++di)
#pragma unroll
                    for (int dj = 0; dj < 4; ++dj)
                        hacc[di][dj] += av[di] * bv[dj];
            }
        }
        __syncthreads();
#pragma unroll
        for (int di = 0; di < 4; ++di)
#pragma unroll
            for (int dj = 0; dj < 4; ++dj) {
                float h = hacc[di][dj] + cb1[j0 + tj * 4 + dj];
                Hs2[ti * 4 + di][tj * 4 + dj] = fmaxf(h, 0.f);
            }
        {
            const int c  = tid >> 3;
            const int jq = (tid & 7) * 8;
            *(float4*)&W2s[c][jq]     = *(const float4*)&cw2[(size_t)c * HHALF + j0 + jq];
            *(float4*)&W2s[c][jq + 4] = *(const float4*)&cw2[(size_t)c * HHALF + j0 + jq + 4];
        }
        __syncthreads();
        float sacc[8];
#pragma unroll
        for (int q = 0; q < 8; ++q) sacc[q] = 0.f;
        for (int j = 0; j < 64; ++j) {
            float h = Hs2[si][j];
#pragma unroll
            for (int q = 0; q < 8; ++q) sacc[q] += h * W2s[sc0 + q][j];
        }
        if (si < M) {
#pragma unroll
            for (int q = 0; q < 8; ++q)
                atomicAdd(&scoresR[(size_t)(rc * 64 + si) * NC + sc0 + q], sacc[q]);
        }
        __syncthreads();
    }
}

__global__ __launch_bounds__(256) void k_refine_fix(
    const int* __restrict__ rcnt, const int* __restrict__ rrows,
    const float* __restrict__ scoresR, const float* __restrict__ cb2,
    int* __restrict__ idx)
{
    const int cnt = min(*rcnt, REFINE_CAP);
    const int t = blockIdx.x * 256 + threadIdx.x;
    if (t >= cnt) return;
    float best = -3.4e38f;
    int bi = 0;
    for (int c = 0; c < NC; ++c) {
        float v = scoresR[(size_t)t * NC + c] + cb2[c];
        if (v > best) { best = v; bi = c; }
    }
    idx[rrows[t]] = bi;
}

__global__ __launch_bounds__(256) void k_counts(const int* __restrict__ idx,
                                                float* __restrict__ counts)
{
    __shared__ int hist[NC];
    if (threadIdx.x < NC) hist[threadIdx.x] = 0;
    __syncthreads();
    const int i = blockIdx.x * 256 + threadIdx.x;
    atomicAdd(&hist[idx[i]], 1);
    __syncthreads();
    if (threadIdx.x < NC)
        atomicAdd(&counts[threadIdx.x], (float)hist[threadIdx.x]);
}

// exclusive prefix of counts -> offsets, cursor (1 block, 32 threads)
__global__ void k_scan(const float* __restrict__ counts,
                       int* __restrict__ offsets, int* __restrict__ cursor)
{
    const int c = threadIdx.x;
    int off = 0;
    for (int j = 0; j < c; ++j) off += (int)counts[j];
    offsets[c] = off;
    cursor[c]  = off;
}

// scatter row ids grouped by centroid
__global__ __launch_bounds__(256) void k_scatter(const int* __restrict__ idx,
                                                 int* __restrict__ cursor,
                                                 int* __restrict__ rowlist)
{
    const int r = blockIdx.x * 256 + threadIdx.x;
    const int c = idx[r];
    const int p = atomicAdd(&cursor[c], 1);
    rowlist[p] = r;
}

// gather-sum: grid (32c x 16 chunks, 2 col-halves). Register accumulation,
// float4 loads of contiguous half-rows, one atomicAdd per owned column.
__global__ __launch_bounds__(256) void k_gather(
    const float* __restrict__ K, const float* __restrict__ V,
    const int* __restrict__ offsets, const float* __restrict__ counts,
    const int* __restrict__ rowlist, float* __restrict__ ksum,
    float* __restrict__ vsum)
{
    const int c     = blockIdx.x & 31;
    const int chunk = blockIdx.x >> 5;
    const int half  = blockIdx.y;
    const int col   = half * 1024 + threadIdx.x * 4;

    const int off = offsets[c];
    const int n   = (int)counts[c];
    const int i0  = off + ((chunk * n) >> 4);
    const int i1  = off + (((chunk + 1) * n) >> 4);

    float ak0 = 0.f, ak1 = 0.f, ak2 = 0.f, ak3 = 0.f;
    float av0 = 0.f, av1 = 0.f, av2 = 0.f, av3 = 0.f;
    for (int i = i0; i < i1; ++i) {
        const int r = rowlist[i];
        const float4 kv = *(const float4*)&K[(size_t)r * HDIM + col];
        const float4 vv = *(const float4*)&V[(size_t)r * HDIM + col];
        ak0 += kv.x; ak1 += kv.y; ak2 += kv.z; ak3 += kv.w;
        av0 += vv.x; av1 += vv.y; av2 += vv.z; av3 += vv.w;
    }
    if (i1 > i0) {
        float* kd = &ksum[(size_t)c * HDIM + col];
        float* vd = &vsum[(size_t)c * HDIM + col];
        atomicAdd(kd + 0, ak0); atomicAdd(kd + 1, ak1);
        atomicAdd(kd + 2, ak2); atomicAdd(kd + 3, ak3);
        atomicAdd(vd + 0, av0); atomicAdd(vd + 1, av1);
        atomicAdd(vd + 2, av2); atomicAdd(vd + 3, av3);
    }
}

__global__ __launch_bounds__(256) void k_final1(float* __restrict__ kc,
                                                float* __restrict__ vc,
                                                const float* __restrict__ counts)
{
    const int e = blockIdx.x * 256 + threadIdx.x;
    const int c = e >> 11;
    const float denom = fmaxf(counts[c], 1.f);
    kc[e] /= denom;
    vc[e] /= denom;
}

__global__ __launch_bounds__(256) void k_final2(
    float* __restrict__ kc, float* __restrict__ vc,
    const float* __restrict__ counts, const float* __restrict__ nk,
    const float* __restrict__ nv)
{
    const int e = blockIdx.x * 256 + threadIdx.x;
    const int c = e >> 11;
    const int h = e & 2047;
    if (counts[c] == 0.f) {
        int src = 0;
        float best = counts[0];
        for (int j = 1; j < NC; ++j) {
            float v = counts[j];
            if (v > best) { best = v; src = j; }
        }
        kc[e] = kc[src * HDIM + h] + 0.1f * nk[e];
        vc[e] = vc[src * HDIM + h] + 0.1f * nv[e];
    }
}

__global__ __launch_bounds__(256) void k_mlp(
    const float* __restrict__ Xk, const float* __restrict__ Xv,
    const float* __restrict__ W, const float* __restrict__ bias,
    float* __restrict__ Ok, float* __restrict__ Ov, int relu)
{
    __shared__ float Xs[32][65];
    __shared__ float Wt[64][65];
    const float* X = blockIdx.y ? Xv : Xk;
    float* O       = blockIdx.y ? Ov : Ok;
    const int tid   = threadIdx.x;
    const int jbase = blockIdx.x * 64;
    const int ti = tid & 7;
    const int tj = tid >> 3;
    float acc[4][2];
#pragma unroll
    for (int a = 0; a < 4; ++a) { acc[a][0] = 0.f; acc[a][1] = 0.f; }

    for (int kt = 0; kt < 32; ++kt) {
        const int k0 = kt * 64;
        __syncthreads();
        {
            const int f4 = tid & 15;
            const int r  = tid >> 4;
#pragma unroll
            for (int rr = 0; rr < 2; ++rr) {
                const int row = r + rr * 16;
                float4 xv = *(const float4*)&X[(size_t)row * HDIM + k0 + f4 * 4];
                Xs[row][f4 * 4 + 0] = xv.x; Xs[row][f4 * 4 + 1] = xv.y;
                Xs[row][f4 * 4 + 2] = xv.z; Xs[row][f4 * 4 + 3] = xv.w;
            }
#pragma unroll
            for (int rr = 0; rr < 4; ++rr) {
                const int row = r + rr * 16;
                float4 wv = *(const float4*)&W[(size_t)(jbase + row) * HDIM + k0 + f4 * 4];
                Wt[row][f4 * 4 + 0] = wv.x; Wt[row][f4 * 4 + 1] = wv.y;
                Wt[row][f4 * 4 + 2] = wv.z; Wt[row][f4 * 4 + 3] = wv.w;
            }
        }
        __syncthreads();
#pragma unroll 8
        for (int k = 0; k < 64; ++k) {
            float a[4], b[2];
#pragma unroll
            for (int d = 0; d < 4; ++d) a[d] = Xs[ti * 4 + d][k];
#pragma unroll
            for (int d = 0; d < 2; ++d) b[d] = Wt[tj * 2 + d][k];
#pragma unroll
            for (int d = 0; d < 4; ++d)
#pragma unroll
                for (int e2 = 0; e2 < 2; ++e2)
                    acc[d][e2] += a[d] * b[e2];
        }
    }
#pragma unroll
    for (int d = 0; d < 4; ++d)
#pragma unroll
        for (int e2 = 0; e2 < 2; ++e2) {
            const int i = ti * 4 + d;
            const int j = jbase + tj * 2 + e2;
            float v = acc[d][e2] + bias[j];
            if (relu) v = fmaxf(v, 0.f);
            O[(size_t)i * HDIM + j] = v;
        }
}

__global__ __launch_bounds__(256) void k_out(
    const float* __restrict__ K, const float* __restrict__ V,
    const float* __restrict__ imp, const int* __restrict__ idx,
    const float* __restrict__ tck, const float* __restrict__ tcv,
    float* __restrict__ ok, float* __restrict__ ov)
{
    const size_t total = (size_t)NROWS * (HDIM / 4);
    for (size_t e = (size_t)blockIdx.x * 256 + threadIdx.x; e < total;
         e += (size_t)gridDim.x * 256) {
        const int r = (int)(e >> 9);
        const int q = (int)(e & 511);
        const bool pass = imp[r] > 0.1f;
        const int c = idx[r];
        const float4* sk = pass ? (const float4*)&K[(size_t)r * HDIM]
                                : (const float4*)&tck[(size_t)c * HDIM];
        const float4* sv = pass ? (const float4*)&V[(size_t)r * HDIM]
                                : (const float4*)&tcv[(size_t)c * HDIM];
        ((float4*)ok)[e] = sk[q];
        ((float4*)ov)[e] = sv[q];
    }
}

extern "C" void kernel_launch(void* const* d_in, const int* in_sizes, int n_in,
                              void* d_out, int out_size, void* d_ws,
                              size_t ws_size, hipStream_t stream)
{
    (void)in_sizes; (void)n_in; (void)out_size; (void)ws_size;
    const float* keys   = (const float*)d_in[0];
    const float* values = (const float*)d_in[1];
    const float* imp    = (const float*)d_in[2];
    const float* cw1    = (const float*)d_in[3];
    const float* cb1    = (const float*)d_in[4];
    const float* cw2    = (const float*)d_in[5];
    const float* cb2    = (const float*)d_in[6];
    const float* tw1    = (const float*)d_in[7];
    const float* tb1    = (const float*)d_in[8];
    const float* tw2    = (const float*)d_in[9];
    const float* tb2    = (const float*)d_in[10];
    const float* nk     = (const float*)d_in[11];
    const float* nv     = (const float*)d_in[12];

    char* ws = (char*)d_ws;
    int*   idx    = (int*)ws;
    float* counts = (float*)(ws + (64 << 10));
    float* kcent  = (float*)(ws + (128 << 10));
    float* vcent  = (float*)(ws + (384 << 10));
    float* hk     = (float*)(ws + (640 << 10));
    float* hv     = (float*)(ws + (896 << 10));
    float* tck    = (float*)(ws + (1152 << 10));
    float* tcv    = (float*)(ws + (1408 << 10));
    const size_t RC_OFF = (size_t)1664 << 10;
    int*   rcnt    = (int*)(ws + RC_OFF);
    int*   rrows   = (int*)(ws + RC_OFF + 4096);
    float* scoresR = (float*)(ws + RC_OFF + 4096 + 8192);

    const size_t MB = (size_t)1 << 20;
    char* ob = (char*)d_out;
    short* khi  = (short*)(ob);
    short* klo  = (short*)(ob + 64 * MB);
    short* hidH = (short*)(ob + 128 * MB);
    short* hidL = (short*)(ob + 160 * MB);
    short* w1hi = (short*)(ob + 192 * MB);
    short* w1lo = (short*)(ob + 196 * MB);
    short* w2hi = (short*)(ob + 200 * MB);
    short* w2lo = (short*)(ob + 200 * MB + (64 << 10));
    float* scoresAll = (float*)(ob + 201 * MB);
    int*   offsets   = (int*)(ob + 204 * MB);
    int*   cursor    = (int*)(ob + 204 * MB + 128);
    int*   rowlist   = (int*)(ob + 204 * MB + 4096);
    float* ok = (float*)d_out;
    float* ov = ok + (size_t)NROWS * HDIM;

    hipMemsetAsync(ws + (64 << 10), 0, (640 - 64) << 10, stream);
    hipMemsetAsync(ws + RC_OFF, 0, 4096 + 8192 + REFINE_CAP * NC * 4, stream);

    k_split<<<2048, 256, 0, stream>>>(keys, khi, klo, NROWS * HDIM / 8);
    k_split<<<512, 256, 0, stream>>>(cw1, w1hi, w1lo, HHALF * HDIM / 8);
    k_split<<<16, 256, 0, stream>>>(cw2, w2hi, w2lo, NC * HHALF / 8);
    k_gemm1<<<1024, 256, 0, stream>>>(khi, klo, w1hi, w1lo, cb1, hidH, hidL);
    k_gemm2<<<NROWS / 128, 256, 0, stream>>>(hidH, hidL, w2hi, w2lo, scoresAll);
    k_argmax<<<NROWS / 256, 256, 0, stream>>>(scoresAll, cb2, idx, rcnt, rrows);
    k_refine_gemm<<<128, 256, 0, stream>>>(keys, cw1, cb1, cw2, rcnt, rrows, scoresR);
    k_refine_fix<<<REFINE_CAP / 256, 256, 0, stream>>>(rcnt, rrows, scoresR, cb2, idx);
    k_counts<<<NROWS / 256, 256, 0, stream>>>(idx, counts);
    k_scan<<<1, 32, 0, stream>>>(counts, offsets, cursor);
    k_scatter<<<NROWS / 256, 256, 0, stream>>>(idx, cursor, rowlist);
    k_gather<<<dim3(32 * 16, 2), 256, 0, stream>>>(keys, values, offsets, counts,
                                                   rowlist, kcent, vcent);
    k_final1<<<(NC * HDIM) / 256, 256, 0, stream>>>(kcent, vcent, counts);
    k_final2<<<(NC * HDIM) / 256, 256, 0, stream>>>(kcent, vcent, counts, nk, nv);
    k_mlp<<<dim3(HDIM / 64, 2), 256, 0, stream>>>(kcent, vcent, tw1, tb1, hk, hv, 1);
    k_mlp<<<dim3(HDIM / 64, 2), 256, 0, stream>>>(hk, hv, tw2, tb2, tck, tcv, 0);
    k_out<<<2048, 256, 0, stream>>>(keys, values, imp, idx, tck, tcv, ok, ov);
}

// Round 5
// 932.850 us; speedup vs baseline: 2.9386x; 1.1218x over previous
//
#include <hip/hip_runtime.h>
#include <hip/hip_bf16.h>

#define NROWS 16384
#define HDIM  2048
#define HHALF 1024
#define NC    32
#define REFINE_TH 0.002f
#define REFINE_CAP 2048

typedef __attribute__((ext_vector_type(8)))  short  short8;
typedef __attribute__((ext_vector_type(16))) float  f32x16;

typedef __attribute__((address_space(3))) void lds_void;
typedef const __attribute__((address_space(1))) void gbl_void;

static __device__ __forceinline__ short f2bf(float f) {
    __hip_bfloat16 h = __float2bfloat16(f);
    return *(short*)&h;
}
static __device__ __forceinline__ float bf2f(short s) {
    union { unsigned int i; float f; } v;
    v.i = ((unsigned int)(unsigned short)s) << 16;
    return v.f;
}
static __device__ __forceinline__ void gload16(const void* g, void* l) {
    __builtin_amdgcn_global_load_lds((gbl_void*)g, (lds_void*)l, 16, 0, 0);
}

// ---------------------------------------------------------------------------
// ws: [0,64K) idx | [64K,+128) counts | [128K,384K) kcent | [384K,640K) vcent
// [640K,896K) hk | [896K,1152K) hv | [1152K,1408K) tck | [1408K,1664K) tcv
// [1664K,+4) rcnt | +4K rrows[2048] | +12K scoresR[2048*32]
//
// d_out (256MB) = big scratch until k_out overwrites it:
// [0,64M) khi | [64M,128M) klo | [128M,160M) hidH | [160M,192M) hidL |
// [192M,196M) w1hi | [196M,200M) w1lo | [200M,+64K) w2hi | +64K w2lo |
// [201M,+2M) scoresAll | [204M,+128) offsets | +128 cursor | +4K rowlist
//
// LDS swizzle (T2, rule-21): global_load_lds writes linearly, so the 16B slot
// permutation is applied to the GLOBAL source address (slot s = base ^ (r&7))
// and the identical XOR on the ds_read side. 32-way -> 4-way conflicts.
// ---------------------------------------------------------------------------

// fp32 -> (bf16 hi, bf16 lo) split, 8 elems/thread, grid-stride
__global__ __launch_bounds__(256) void k_split(const float* __restrict__ src,
                                               short* __restrict__ hi,
                                               short* __restrict__ lo, int n8)
{
    const int stride = gridDim.x * 256;
    for (int i = blockIdx.x * 256 + threadIdx.x; i < n8; i += stride) {
        float4 a = ((const float4*)src)[(size_t)i * 2];
        float4 b = ((const float4*)src)[(size_t)i * 2 + 1];
        float f[8] = {a.x, a.y, a.z, a.w, b.x, b.y, b.z, b.w};
        short h[8], l[8];
#pragma unroll
        for (int e = 0; e < 8; ++e) {
            h[e] = f2bf(f[e]);
            l[e] = f2bf(f[e] - bf2f(h[e]));
        }
        *(short8*)&hi[(size_t)i * 8] = *(short8*)h;
        *(short8*)&lo[(size_t)i * 8] = *(short8*)l;
    }
}

// GEMM1: hidden[16384,1024] = relu(K @ w1^T + b1), 3-split bf16 MFMA.
// 128x128 tile, BK=64, swizzled LDS slots (4-way max conflicts).
__global__ __launch_bounds__(256) void k_gemm1(
    const short* __restrict__ khi, const short* __restrict__ klo,
    const short* __restrict__ w1hi, const short* __restrict__ w1lo,
    const float* __restrict__ cb1, short* __restrict__ hidH,
    short* __restrict__ hidL)
{
    __shared__ alignas(16) short Ah[128 * 64];
    __shared__ alignas(16) short Al[128 * 64];
    __shared__ alignas(16) short Bh[128 * 64];
    __shared__ alignas(16) short Bl[128 * 64];

    const int tid = threadIdx.x;
    const int w = tid >> 6, lane = tid & 63;
    const int wr = w & 1, wc = w >> 1;
    const int l31 = lane & 31, lq5 = lane >> 5;

    const int d = blockIdx.x;
    const int xcd = d & 7, t = d >> 3;
    const int jb = t >> 4;
    const int rb = ((t & 15) << 3) | xcd;
    const int row0 = rb * 128, col0 = jb * 128;

    // staging: chunk c = w*4+q covers rows c*8..c*8+7 (128B each).
    // slot s = (lane&7) ^ (r&7), r&7 == lane>>3  -> pre-swizzled source.
    const int st_r   = (tid >> 3) & 15;          // placeholder (recomputed)
    (void)st_r;
    const int s_swz  = (lane & 7) ^ (lane >> 3); // global slot for this lane

    f32x16 acc[2][2] = {};

    for (int kt = 0; kt < 32; ++kt) {
        const int k0 = kt * 64;
        __syncthreads();
#pragma unroll
        for (int q = 0; q < 4; ++q) {
            const int c = w * 4 + q;
            const int r = c * 8 + (lane >> 3);
            const size_t ga = ((size_t)(row0 + r) * HDIM + k0) * 2 + s_swz * 16;
            const size_t gb = ((size_t)(col0 + r) * HDIM + k0) * 2 + s_swz * 16;
            gload16((const char*)khi + ga, &Ah[c * 512]);
            gload16((const char*)klo + ga, &Al[c * 512]);
            gload16((const char*)w1hi + gb, &Bh[c * 512]);
            gload16((const char*)w1lo + gb, &Bl[c * 512]);
        }
        __syncthreads();
#pragma unroll
        for (int ks = 0; ks < 4; ++ks) {
            const int sw = (((ks * 2 + lq5) ^ (l31 & 7)) << 3);
            short8 aH[2], aL[2], bH[2], bL[2];
#pragma unroll
            for (int m = 0; m < 2; ++m) {
                const int rr = wr * 64 + m * 32 + l31;
                aH[m] = *(const short8*)&Ah[rr * 64 + sw];
                aL[m] = *(const short8*)&Al[rr * 64 + sw];
            }
#pragma unroll
            for (int n = 0; n < 2; ++n) {
                const int cc = wc * 64 + n * 32 + l31;
                bH[n] = *(const short8*)&Bh[cc * 64 + sw];
                bL[n] = *(const short8*)&Bl[cc * 64 + sw];
            }
#pragma unroll
            for (int m = 0; m < 2; ++m)
#pragma unroll
                for (int n = 0; n < 2; ++n) {
                    acc[m][n] = __builtin_amdgcn_mfma_f32_32x32x16_bf16(aH[m], bH[n], acc[m][n], 0, 0, 0);
                    acc[m][n] = __builtin_amdgcn_mfma_f32_32x32x16_bf16(aH[m], bL[n], acc[m][n], 0, 0, 0);
                    acc[m][n] = __builtin_amdgcn_mfma_f32_32x32x16_bf16(aL[m], bH[n], acc[m][n], 0, 0, 0);
                }
        }
    }
#pragma unroll
    for (int n = 0; n < 2; ++n) {
        const int col = col0 + wc * 64 + n * 32 + l31;
        const float bias = cb1[col];
#pragma unroll
        for (int m = 0; m < 2; ++m) {
#pragma unroll
            for (int r = 0; r < 16; ++r) {
                const int row = row0 + wr * 64 + m * 32 + (r & 3) + 8 * (r >> 2) + 4 * lq5;
                float h = acc[m][n][r] + bias;
                h = fmaxf(h, 0.f);
                const short hh = f2bf(h);
                hidH[(size_t)row * HHALF + col] = hh;
                hidL[(size_t)row * HHALF + col] = f2bf(h - bf2f(hh));
            }
        }
    }
}

// GEMM2: scoresAll[16384,32] = hidden @ w2^T (3-split bf16 MFMA).
// 64 rows/block x 256 blocks. 4 waves = 2 row-groups x 2 k-halves,
// LDS partial reduction. Swizzled slots (rows are 256B = 16 slots).
__global__ __launch_bounds__(256) void k_gemm2(
    const short* __restrict__ hidH, const short* __restrict__ hidL,
    const short* __restrict__ w2hi, const short* __restrict__ w2lo,
    float* __restrict__ scoresAll)
{
    __shared__ alignas(16) short HsH[64 * 128];
    __shared__ alignas(16) short HsL[64 * 128];
    __shared__ alignas(16) short W2h[32 * 128];
    __shared__ alignas(16) short W2l[32 * 128];
    __shared__ float ScL[2][64][32];

    const int tid = threadIdx.x;
    const int w = tid >> 6, lane = tid & 63;
    const int l31 = lane & 31, lq5 = lane >> 5;
    const int wr = w & 1;    // row group (32 rows)
    const int wk = w >> 1;   // k half (64 shorts of each 128-tile)
    const int row0 = blockIdx.x * 64;

    f32x16 sacc = {};

    for (int jt = 0; jt < 8; ++jt) {
        const int kk0 = jt * 128;
        __syncthreads();
        // stage hidden 64 rows x 256B (16 chunks) with slot swizzle
#pragma unroll
        for (int q = 0; q < 4; ++q) {
            const int c = w * 4 + q;
            const int r = c * 4 + (lane >> 4);
            const int s = (lane & 15) ^ (r & 7);
            const size_t g = ((size_t)(row0 + r) * HHALF + kk0) * 2 + s * 16;
            gload16((const char*)hidH + g, &HsH[c * 512]);
            gload16((const char*)hidL + g, &HsL[c * 512]);
        }
        // stage w2 32 rows x 256B (8 chunks)
#pragma unroll
        for (int q = 0; q < 2; ++q) {
            const int c = w * 2 + q;
            const int r = c * 4 + (lane >> 4);
            const int s = (lane & 15) ^ (r & 7);
            const size_t g = ((size_t)r * HHALF + kk0) * 2 + s * 16;
            gload16((const char*)w2hi + g, &W2h[c * 512]);
            gload16((const char*)w2lo + g, &W2l[c * 512]);
        }
        __syncthreads();
#pragma unroll
        for (int ks = 0; ks < 4; ++ks) {
            const int slot = wk * 8 + ks * 2 + lq5;
            const int sw = ((slot ^ (l31 & 7)) << 3);
            short8 aH = *(const short8*)&HsH[(wr * 32 + l31) * 128 + sw];
            short8 aL = *(const short8*)&HsL[(wr * 32 + l31) * 128 + sw];
            short8 bH = *(const short8*)&W2h[l31 * 128 + sw];
            short8 bL = *(const short8*)&W2l[l31 * 128 + sw];
            sacc = __builtin_amdgcn_mfma_f32_32x32x16_bf16(aH, bH, sacc, 0, 0, 0);
            sacc = __builtin_amdgcn_mfma_f32_32x32x16_bf16(aH, bL, sacc, 0, 0, 0);
            sacc = __builtin_amdgcn_mfma_f32_32x32x16_bf16(aL, bH, sacc, 0, 0, 0);
        }
    }
    // partials -> LDS, reduce k-halves, write scores
#pragma unroll
    for (int r = 0; r < 16; ++r) {
        const int rowL = wr * 32 + (r & 3) + 8 * (r >> 2) + 4 * lq5;
        ScL[wk][rowL][l31] = sacc[r];
    }
    __syncthreads();
    for (int e = tid; e < 64 * NC; e += 256) {
        const int row = e >> 5, c = e & 31;
        scoresAll[(size_t)(row0 + row) * NC + c] = ScL[0][row][c] + ScL[1][row][c];
    }
}

// argmax + low-margin flagging
__global__ __launch_bounds__(256) void k_argmax(
    const float* __restrict__ scoresAll, const float* __restrict__ cb2,
    int* __restrict__ idx, int* __restrict__ rcnt, int* __restrict__ rrows)
{
    const int row = blockIdx.x * 256 + threadIdx.x;
    const float4* s4 = (const float4*)&scoresAll[(size_t)row * NC];
    float best = -3.4e38f, second = -3.4e38f;
    int bi = 0;
#pragma unroll
    for (int q = 0; q < 8; ++q) {
        float4 v = s4[q];
        float vv[4] = {v.x, v.y, v.z, v.w};
#pragma unroll
        for (int e = 0; e < 4; ++e) {
            const int c = q * 4 + e;
            const float s = vv[e] + cb2[c];
            if (s > best) { second = best; best = s; bi = c; }
            else if (s > second) second = s;
        }
    }
    idx[row] = bi;
    if (best - second < REFINE_TH) {
        int slot = atomicAdd(rcnt, 1);
        if (slot < REFINE_CAP) rrows[slot] = row;
    }
}

// exact fp32 recompute of scores for flagged rows (expected ~0 rows)
__global__ __launch_bounds__(256) void k_refine_gemm(
    const float* __restrict__ K, const float* __restrict__ cw1,
    const float* __restrict__ cb1, const float* __restrict__ cw2,
    const int* __restrict__ rcnt, const int* __restrict__ rrows,
    float* __restrict__ scoresR)
{
    const int cnt = min(*rcnt, REFINE_CAP);
    if (cnt == 0) return;
    const int units = ((cnt + 63) >> 6) * 16;
    __shared__ float KsT[64][68];
    __shared__ float WsT[64][68];
    __shared__ float Hs2[64][68];
    __shared__ float W2s[NC][68];

    const int tid = threadIdx.x;
    const int ti = tid & 15, tj = tid >> 4;
    const int si = tid & 63, sc0 = (tid >> 6) * 8;

    for (int u = blockIdx.x; u < units; u += gridDim.x) {
        const int rc = u >> 4, jt = u & 15, j0 = jt * 64;
        const int M = min(cnt - rc * 64, 64);

        float hacc[4][4];
#pragma unroll
        for (int a = 0; a < 4; ++a)
#pragma unroll
            for (int b = 0; b < 4; ++b) hacc[a][b] = 0.f;

        for (int kt = 0; kt < 32; ++kt) {
            const int k0 = kt * 64;
            __syncthreads();
            {
                const int r  = tid >> 2;
                const int kb = (tid & 3) * 16;
                const int grow = rrows[rc * 64 + min(r, M - 1)];
#pragma unroll
                for (int q = 0; q < 4; ++q) {
                    float4 v = *(const float4*)&K[(size_t)grow * HDIM + k0 + kb + q * 4];
                    KsT[kb + q * 4 + 0][r] = v.x; KsT[kb + q * 4 + 1][r] = v.y;
                    KsT[kb + q * 4 + 2][r] = v.z; KsT[kb + q * 4 + 3][r] = v.w;
                }
                const int j = tid >> 2;
#pragma unroll
                for (int q = 0; q < 4; ++q) {
                    float4 v = *(const float4*)&cw1[(size_t)(j0 + j) * HDIM + k0 + kb + q * 4];
                    WsT[kb + q * 4 + 0][j] = v.x; WsT[kb + q * 4 + 1][j] = v.y;
                    WsT[kb + q * 4 + 2][j] = v.z; WsT[kb + q * 4 + 3][j] = v.w;
                }
            }
            __syncthreads();
#pragma unroll 4
            for (int k = 0; k < 64; ++k) {
                float4 a = *(float4*)&KsT[k][ti * 4];
                float4 b = *(float4*)&WsT[k][tj * 4];
                float av[4] = {a.x, a.y, a.z, a.w};
                float bv[4] = {b.x, b.y, b.z, b.w};
#pragma unroll
                for (int di = 0; di < 4; ++di)
#pragma unroll
                    for (int dj = 0; dj < 4; ++dj)
                        hacc[di][dj] += av[di] * bv[dj];
            }
        }
        __syncthreads();
#pragma unroll
        for (int di = 0; di < 4; ++di)
#pragma unroll
            for (int dj = 0; dj < 4; ++dj) {
                float h = hacc[di][dj] + cb1[j0 + tj * 4 + dj];
                Hs2[ti * 4 + di][tj * 4 + dj] = fmaxf(h, 0.f);
            }
        {
            const int c  = tid >> 3;
            const int jq = (tid & 7) * 8;
            *(float4*)&W2s[c][jq]     = *(const float4*)&cw2[(size_t)c * HHALF + j0 + jq];
            *(float4*)&W2s[c][jq + 4] = *(const float4*)&cw2[(size_t)c * HHALF + j0 + jq + 4];
        }
        __syncthreads();
        float sacc[8];
#pragma unroll
        for (int q = 0; q < 8; ++q) sacc[q] = 0.f;
        for (int j = 0; j < 64; ++j) {
            float h = Hs2[si][j];
#pragma unroll
            for (int q = 0; q < 8; ++q) sacc[q] += h * W2s[sc0 + q][j];
        }
        if (si < M) {
#pragma unroll
            for (int q = 0; q < 8; ++q)
                atomicAdd(&scoresR[(size_t)(rc * 64 + si) * NC + sc0 + q], sacc[q]);
        }
        __syncthreads();
    }
}

__global__ __launch_bounds__(256) void k_refine_fix(
    const int* __restrict__ rcnt, const int* __restrict__ rrows,
    const float* __restrict__ scoresR, const float* __restrict__ cb2,
    int* __restrict__ idx)
{
    const int cnt = min(*rcnt, REFINE_CAP);
    const int t = blockIdx.x * 256 + threadIdx.x;
    if (t >= cnt) return;
    float best = -3.4e38f;
    int bi = 0;
    for (int c = 0; c < NC; ++c) {
        float v = scoresR[(size_t)t * NC + c] + cb2[c];
        if (v > best) { best = v; bi = c; }
    }
    idx[rrows[t]] = bi;
}

__global__ __launch_bounds__(256) void k_counts(const int* __restrict__ idx,
                                                float* __restrict__ counts)
{
    __shared__ int hist[NC];
    if (threadIdx.x < NC) hist[threadIdx.x] = 0;
    __syncthreads();
    const int i = blockIdx.x * 256 + threadIdx.x;
    atomicAdd(&hist[idx[i]], 1);
    __syncthreads();
    if (threadIdx.x < NC)
        atomicAdd(&counts[threadIdx.x], (float)hist[threadIdx.x]);
}

__global__ void k_scan(const float* __restrict__ counts,
                       int* __restrict__ offsets, int* __restrict__ cursor)
{
    const int c = threadIdx.x;
    int off = 0;
    for (int j = 0; j < c; ++j) off += (int)counts[j];
    offsets[c] = off;
    cursor[c]  = off;
}

__global__ __launch_bounds__(256) void k_scatter(const int* __restrict__ idx,
                                                 int* __restrict__ cursor,
                                                 int* __restrict__ rowlist)
{
    const int r = blockIdx.x * 256 + threadIdx.x;
    const int c = idx[r];
    const int p = atomicAdd(&cursor[c], 1);
    rowlist[p] = r;
}

// gather-sum: grid (32c x 16 chunks, 2 col-halves), register accumulation
__global__ __launch_bounds__(256) void k_gather(
    const float* __restrict__ K, const float* __restrict__ V,
    const int* __restrict__ offsets, const float* __restrict__ counts,
    const int* __restrict__ rowlist, float* __restrict__ ksum,
    float* __restrict__ vsum)
{
    const int c     = blockIdx.x & 31;
    const int chunk = blockIdx.x >> 5;
    const int half  = blockIdx.y;
    const int col   = half * 1024 + threadIdx.x * 4;

    const int off = offsets[c];
    const int n   = (int)counts[c];
    const int i0  = off + ((chunk * n) >> 4);
    const int i1  = off + (((chunk + 1) * n) >> 4);

    float ak0 = 0.f, ak1 = 0.f, ak2 = 0.f, ak3 = 0.f;
    float av0 = 0.f, av1 = 0.f, av2 = 0.f, av3 = 0.f;
    for (int i = i0; i < i1; ++i) {
        const int r = rowlist[i];
        const float4 kv = *(const float4*)&K[(size_t)r * HDIM + col];
        const float4 vv = *(const float4*)&V[(size_t)r * HDIM + col];
        ak0 += kv.x; ak1 += kv.y; ak2 += kv.z; ak3 += kv.w;
        av0 += vv.x; av1 += vv.y; av2 += vv.z; av3 += vv.w;
    }
    if (i1 > i0) {
        float* kd = &ksum[(size_t)c * HDIM + col];
        float* vd = &vsum[(size_t)c * HDIM + col];
        atomicAdd(kd + 0, ak0); atomicAdd(kd + 1, ak1);
        atomicAdd(kd + 2, ak2); atomicAdd(kd + 3, ak3);
        atomicAdd(vd + 0, av0); atomicAdd(vd + 1, av1);
        atomicAdd(vd + 2, av2); atomicAdd(vd + 3, av3);
    }
}

__global__ __launch_bounds__(256) void k_final1(float* __restrict__ kc,
                                                float* __restrict__ vc,
                                                const float* __restrict__ counts)
{
    const int e = blockIdx.x * 256 + threadIdx.x;
    const int c = e >> 11;
    const float denom = fmaxf(counts[c], 1.f);
    kc[e] /= denom;
    vc[e] /= denom;
}

__global__ __launch_bounds__(256) void k_final2(
    float* __restrict__ kc, float* __restrict__ vc,
    const float* __restrict__ counts, const float* __restrict__ nk,
    const float* __restrict__ nv)
{
    const int e = blockIdx.x * 256 + threadIdx.x;
    const int c = e >> 11;
    const int h = e & 2047;
    if (counts[c] == 0.f) {
        int src = 0;
        float best = counts[0];
        for (int j = 1; j < NC; ++j) {
            float v = counts[j];
            if (v > best) { best = v; src = j; }
        }
        kc[e] = kc[src * HDIM + h] + 0.1f * nk[e];
        vc[e] = vc[src * HDIM + h] + 0.1f * nv[e];
    }
}

__global__ __launch_bounds__(256) void k_mlp(
    const float* __restrict__ Xk, const float* __restrict__ Xv,
    const float* __restrict__ W, const float* __restrict__ bias,
    float* __restrict__ Ok, float* __restrict__ Ov, int relu)
{
    __shared__ float Xs[32][65];
    __shared__ float Wt[64][65];
    const float* X = blockIdx.y ? Xv : Xk;
    float* O       = blockIdx.y ? Ov : Ok;
    const int tid   = threadIdx.x;
    const int jbase = blockIdx.x * 64;
    const int ti = tid & 7;
    const int tj = tid >> 3;
    float acc[4][2];
#pragma unroll
    for (int a = 0; a < 4; ++a) { acc[a][0] = 0.f; acc[a][1] = 0.f; }

    for (int kt = 0; kt < 32; ++kt) {
        const int k0 = kt * 64;
        __syncthreads();
        {
            const int f4 = tid & 15;
            const int r  = tid >> 4;
#pragma unroll
            for (int rr = 0; rr < 2; ++rr) {
                const int row = r + rr * 16;
                float4 xv = *(const float4*)&X[(size_t)row * HDIM + k0 + f4 * 4];
                Xs[row][f4 * 4 + 0] = xv.x; Xs[row][f4 * 4 + 1] = xv.y;
                Xs[row][f4 * 4 + 2] = xv.z; Xs[row][f4 * 4 + 3] = xv.w;
            }
#pragma unroll
            for (int rr = 0; rr < 4; ++rr) {
                const int row = r + rr * 16;
                float4 wv = *(const float4*)&W[(size_t)(jbase + row) * HDIM + k0 + f4 * 4];
                Wt[row][f4 * 4 + 0] = wv.x; Wt[row][f4 * 4 + 1] = wv.y;
                Wt[row][f4 * 4 + 2] = wv.z; Wt[row][f4 * 4 + 3] = wv.w;
            }
        }
        __syncthreads();
#pragma unroll 8
        for (int k = 0; k < 64; ++k) {
            float a[4], b[2];
#pragma unroll
            for (int d = 0; d < 4; ++d) a[d] = Xs[ti * 4 + d][k];
#pragma unroll
            for (int d = 0; d < 2; ++d) b[d] = Wt[tj * 2 + d][k];
#pragma unroll
            for (int d = 0; d < 4; ++d)
#pragma unroll
                for (int e2 = 0; e2 < 2; ++e2)
                    acc[d][e2] += a[d] * b[e2];
        }
    }
#pragma unroll
    for (int d = 0; d < 4; ++d)
#pragma unroll
        for (int e2 = 0; e2 < 2; ++e2) {
            const int i = ti * 4 + d;
            const int j = jbase + tj * 2 + e2;
            float v = acc[d][e2] + bias[j];
            if (relu) v = fmaxf(v, 0.f);
            O[(size_t)i * HDIM + j] = v;
        }
}

__global__ __launch_bounds__(256) void k_out(
    const float* __restrict__ K, const float* __restrict__ V,
    const float* __restrict__ imp, const int* __restrict__ idx,
    const float* __restrict__ tck, const float* __restrict__ tcv,
    float* __restrict__ ok, float* __restrict__ ov)
{
    const size_t total = (size_t)NROWS * (HDIM / 4);
    for (size_t e = (size_t)blockIdx.x * 256 + threadIdx.x; e < total;
         e += (size_t)gridDim.x * 256) {
        const int r = (int)(e >> 9);
        const int q = (int)(e & 511);
        const bool pass = imp[r] > 0.1f;
        const int c = idx[r];
        const float4* sk = pass ? (const float4*)&K[(size_t)r * HDIM]
                                : (const float4*)&tck[(size_t)c * HDIM];
        const float4* sv = pass ? (const float4*)&V[(size_t)r * HDIM]
                                : (const float4*)&tcv[(size_t)c * HDIM];
        ((float4*)ok)[e] = sk[q];
        ((float4*)ov)[e] = sv[q];
    }
}

extern "C" void kernel_launch(void* const* d_in, const int* in_sizes, int n_in,
                              void* d_out, int out_size, void* d_ws,
                              size_t ws_size, hipStream_t stream)
{
    (void)in_sizes; (void)n_in; (void)out_size; (void)ws_size;
    const float* keys   = (const float*)d_in[0];
    const float* values = (const float*)d_in[1];
    const float* imp    = (const float*)d_in[2];
    const float* cw1    = (const float*)d_in[3];
    const float* cb1    = (const float*)d_in[4];
    const float* cw2    = (const float*)d_in[5];
    const float* cb2    = (const float*)d_in[6];
    const float* tw1    = (const float*)d_in[7];
    const float* tb1    = (const float*)d_in[8];
    const float* tw2    = (const float*)d_in[9];
    const float* tb2    = (const float*)d_in[10];
    const float* nk     = (const float*)d_in[11];
    const float* nv     = (const float*)d_in[12];

    char* ws = (char*)d_ws;
    int*   idx    = (int*)ws;
    float* counts = (float*)(ws + (64 << 10));
    float* kcent  = (float*)(ws + (128 << 10));
    float* vcent  = (float*)(ws + (384 << 10));
    float* hk     = (float*)(ws + (640 << 10));
    float* hv     = (float*)(ws + (896 << 10));
    float* tck    = (float*)(ws + (1152 << 10));
    float* tcv    = (float*)(ws + (1408 << 10));
    const size_t RC_OFF = (size_t)1664 << 10;
    int*   rcnt    = (int*)(ws + RC_OFF);
    int*   rrows   = (int*)(ws + RC_OFF + 4096);
    float* scoresR = (float*)(ws + RC_OFF + 4096 + 8192);

    const size_t MB = (size_t)1 << 20;
    char* ob = (char*)d_out;
    short* khi  = (short*)(ob);
    short* klo  = (short*)(ob + 64 * MB);
    short* hidH = (short*)(ob + 128 * MB);
    short* hidL = (short*)(ob + 160 * MB);
    short* w1hi = (short*)(ob + 192 * MB);
    short* w1lo = (short*)(ob + 196 * MB);
    short* w2hi = (short*)(ob + 200 * MB);
    short* w2lo = (short*)(ob + 200 * MB + (64 << 10));
    float* scoresAll = (float*)(ob + 201 * MB);
    int*   offsets   = (int*)(ob + 204 * MB);
    int*   cursor    = (int*)(ob + 204 * MB + 128);
    int*   rowlist   = (int*)(ob + 204 * MB + 4096);
    float* ok = (float*)d_out;
    float* ov = ok + (size_t)NROWS * HDIM;

    hipMemsetAsync(ws + (64 << 10), 0, (640 - 64) << 10, stream);
    hipMemsetAsync(ws + RC_OFF, 0, 4096 + 8192 + REFINE_CAP * NC * 4, stream);

    k_split<<<2048, 256, 0, stream>>>(keys, khi, klo, NROWS * HDIM / 8);
    k_split<<<512, 256, 0, stream>>>(cw1, w1hi, w1lo, HHALF * HDIM / 8);
    k_split<<<16, 256, 0, stream>>>(cw2, w2hi, w2lo, NC * HHALF / 8);
    k_gemm1<<<1024, 256, 0, stream>>>(khi, klo, w1hi, w1lo, cb1, hidH, hidL);
    k_gemm2<<<NROWS / 64, 256, 0, stream>>>(hidH, hidL, w2hi, w2lo, scoresAll);
    k_argmax<<<NROWS / 256, 256, 0, stream>>>(scoresAll, cb2, idx, rcnt, rrows);
    k_refine_gemm<<<128, 256, 0, stream>>>(keys, cw1, cb1, cw2, rcnt, rrows, scoresR);
    k_refine_fix<<<REFINE_CAP / 256, 256, 0, stream>>>(rcnt, rrows, scoresR, cb2, idx);
    k_counts<<<NROWS / 256, 256, 0, stream>>>(idx, counts);
    k_scan<<<1, 32, 0, stream>>>(counts, offsets, cursor);
    k_scatter<<<NROWS / 256, 256, 0, stream>>>(idx, cursor, rowlist);
    k_gather<<<dim3(32 * 16, 2), 256, 0, stream>>>(keys, values, offsets, counts,
                                                   rowlist, kcent, vcent);
    k_final1<<<(NC * HDIM) / 256, 256, 0, stream>>>(kcent, vcent, counts);
    k_final2<<<(NC * HDIM) / 256, 256, 0, stream>>>(kcent, vcent, counts, nk, nv);
    k_mlp<<<dim3(HDIM / 64, 2), 256, 0, stream>>>(kcent, vcent, tw1, tb1, hk, hv, 1);
    k_mlp<<<dim3(HDIM / 64, 2), 256, 0, stream>>>(hk, hv, tw2, tb2, tck, tcv, 0);
    k_out<<<2048, 256, 0, stream>>>(keys, values, imp, idx, tck, tcv, ok, ov);
}

// Round 6
// 662.189 us; speedup vs baseline: 4.1398x; 1.4087x over previous
//
#include <hip/hip_runtime.h>
#include <hip/hip_bf16.h>

#define NROWS 16384
#define HDIM  2048
#define HHALF 1024
#define NC    32
#define REFINE_TH 0.012f
#define REFINE_CAP 16384

typedef __attribute__((ext_vector_type(8)))  short  short8;
typedef __attribute__((ext_vector_type(16))) float  f32x16;

typedef __attribute__((address_space(3))) void lds_void;
typedef const __attribute__((address_space(1))) void gbl_void;

static __device__ __forceinline__ short f2h(float f) {
    _Float16 h = (_Float16)f;
    return *(short*)&h;
}
static __device__ __forceinline__ void gload16(const void* g, void* l) {
    __builtin_amdgcn_global_load_lds((gbl_void*)g, (lds_void*)l, 16, 0, 0);
}

// ---------------------------------------------------------------------------
// ws: [0,64K) idx | [64K,+128) counts | [128K,384K) kcent | [384K,640K) vcent
// [640K,896K) hk | [896K,1152K) hv | [1152K,1408K) tck | [1408K,1664K) tcv
//
// d_out (256MiB) = scratch until k_out overwrites it:
// [0,64M) kh (fp16 keys) | [128M,160M) hidH (fp16) | [192M,196M) w1h |
// [200M,+64K) w2h | [201M,+2M) scoresAll |
// [204M: +0 offsets, +128 cursor, +256 rcnt, +1K rrows[16384],
//        +80K rowlist[16384], +256K scoresR[16384*32] (2MB)]
// All consumed before k_out runs.
// ---------------------------------------------------------------------------

// fp32 -> fp16, 8 elems/thread, grid-stride
__global__ __launch_bounds__(256) void k_split_h(const float* __restrict__ src,
                                                 short* __restrict__ dst, int n8)
{
    const int stride = gridDim.x * 256;
    for (int i = blockIdx.x * 256 + threadIdx.x; i < n8; i += stride) {
        float4 a = ((const float4*)src)[(size_t)i * 2];
        float4 b = ((const float4*)src)[(size_t)i * 2 + 1];
        float f[8] = {a.x, a.y, a.z, a.w, b.x, b.y, b.z, b.w};
        short h[8];
#pragma unroll
        for (int e = 0; e < 8; ++e) h[e] = f2h(f[e]);
        *(short8*)&dst[(size_t)i * 8] = *(short8*)h;
    }
}

// GEMM1: hidden[16384,1024] = relu(K @ w1^T + b1), single fp16 MFMA.
// 128x128 tile, BK=64, 32KB LDS -> 4 blocks/CU. Swizzled slots (4-way max).
__global__ __launch_bounds__(256) void k_gemm1(
    const short* __restrict__ kh, const short* __restrict__ w1h,
    const float* __restrict__ cb1, short* __restrict__ hidH)
{
    __shared__ alignas(16) short Ah[128 * 64];
    __shared__ alignas(16) short Bh[128 * 64];

    const int tid = threadIdx.x;
    const int w = tid >> 6, lane = tid & 63;
    const int wr = w & 1, wc = w >> 1;
    const int l31 = lane & 31, lq5 = lane >> 5;

    const int d = blockIdx.x;
    const int xcd = d & 7, t = d >> 3;
    const int jb = t >> 4;
    const int rb = ((t & 15) << 3) | xcd;
    const int row0 = rb * 128, col0 = jb * 128;

    const int s_swz = (lane & 7) ^ (lane >> 3);  // pre-swizzled source slot

    f32x16 acc[2][2] = {};

    for (int kt = 0; kt < 32; ++kt) {
        const int k0 = kt * 64;
        __syncthreads();
#pragma unroll
        for (int q = 0; q < 4; ++q) {
            const int c = w * 4 + q;
            const int r = c * 8 + (lane >> 3);
            const size_t ga = ((size_t)(row0 + r) * HDIM + k0) * 2 + s_swz * 16;
            const size_t gb = ((size_t)(col0 + r) * HDIM + k0) * 2 + s_swz * 16;
            gload16((const char*)kh + ga, &Ah[c * 512]);
            gload16((const char*)w1h + gb, &Bh[c * 512]);
        }
        __syncthreads();
#pragma unroll
        for (int ks = 0; ks < 4; ++ks) {
            const int sw = (((ks * 2 + lq5) ^ (l31 & 7)) << 3);
            short8 aH[2], bH[2];
#pragma unroll
            for (int m = 0; m < 2; ++m)
                aH[m] = *(const short8*)&Ah[(wr * 64 + m * 32 + l31) * 64 + sw];
#pragma unroll
            for (int n = 0; n < 2; ++n)
                bH[n] = *(const short8*)&Bh[(wc * 64 + n * 32 + l31) * 64 + sw];
#pragma unroll
            for (int m = 0; m < 2; ++m)
#pragma unroll
                for (int n = 0; n < 2; ++n)
                    acc[m][n] = __builtin_amdgcn_mfma_f32_32x32x16_f16(aH[m], bH[n], acc[m][n], 0, 0, 0);
        }
    }
#pragma unroll
    for (int n = 0; n < 2; ++n) {
        const int col = col0 + wc * 64 + n * 32 + l31;
        const float bias = cb1[col];
#pragma unroll
        for (int m = 0; m < 2; ++m) {
#pragma unroll
            for (int r = 0; r < 16; ++r) {
                const int row = row0 + wr * 64 + m * 32 + (r & 3) + 8 * (r >> 2) + 4 * lq5;
                float h = acc[m][n][r] + bias;
                hidH[(size_t)row * HHALF + col] = f2h(fmaxf(h, 0.f));
            }
        }
    }
}

// GEMM2: scoresAll[16384,32] = hidden @ w2^T (single fp16 MFMA).
// 64 rows/block x 256 blocks; 4 waves = 2 rowgroups x 2 khalves; 40KB LDS.
// 256B rows = 16 slots -> XOR row&15 swizzle (2-way, free).
__global__ __launch_bounds__(256) void k_gemm2(
    const short* __restrict__ hidH, const short* __restrict__ w2h,
    float* __restrict__ scoresAll)
{
    __shared__ alignas(16) short Hs[64 * 128];
    __shared__ alignas(16) short W2s[32 * 128];
    __shared__ float ScL[2][64][32];

    const int tid = threadIdx.x;
    const int w = tid >> 6, lane = tid & 63;
    const int l31 = lane & 31, lq5 = lane >> 5;
    const int wr = w & 1;    // row group
    const int wk = w >> 1;   // k half
    const int row0 = blockIdx.x * 64;

    f32x16 sacc = {};

    for (int jt = 0; jt < 8; ++jt) {
        const int kk0 = jt * 128;
        __syncthreads();
#pragma unroll
        for (int q = 0; q < 4; ++q) {
            const int c = w * 4 + q;
            const int r = c * 4 + (lane >> 4);
            const int s = (lane & 15) ^ (r & 15);
            const size_t g = ((size_t)(row0 + r) * HHALF + kk0) * 2 + s * 16;
            gload16((const char*)hidH + g, &Hs[c * 512]);
        }
#pragma unroll
        for (int q = 0; q < 2; ++q) {
            const int c = w * 2 + q;
            const int r = c * 4 + (lane >> 4);
            const int s = (lane & 15) ^ (r & 15);
            const size_t g = ((size_t)r * HHALF + kk0) * 2 + s * 16;
            gload16((const char*)w2h + g, &W2s[c * 512]);
        }
        __syncthreads();
#pragma unroll
        for (int ks = 0; ks < 4; ++ks) {
            const int slot = wk * 8 + ks * 2 + lq5;
            const int sw = ((slot ^ (l31 & 15)) << 3);
            short8 aH = *(const short8*)&Hs[(wr * 32 + l31) * 128 + sw];
            short8 bH = *(const short8*)&W2s[l31 * 128 + sw];
            sacc = __builtin_amdgcn_mfma_f32_32x32x16_f16(aH, bH, sacc, 0, 0, 0);
        }
    }
#pragma unroll
    for (int r = 0; r < 16; ++r) {
        const int rowL = wr * 32 + (r & 3) + 8 * (r >> 2) + 4 * lq5;
        ScL[wk][rowL][l31] = sacc[r];
    }
    __syncthreads();
    for (int e = tid; e < 64 * NC; e += 256) {
        const int row = e >> 5, c = e & 31;
        scoresAll[(size_t)(row0 + row) * NC + c] = ScL[0][row][c] + ScL[1][row][c];
    }
}

// argmax + low-margin flagging
__global__ __launch_bounds__(256) void k_argmax(
    const float* __restrict__ scoresAll, const float* __restrict__ cb2,
    int* __restrict__ idx, int* __restrict__ rcnt, int* __restrict__ rrows)
{
    const int row = blockIdx.x * 256 + threadIdx.x;
    const float4* s4 = (const float4*)&scoresAll[(size_t)row * NC];
    float best = -3.4e38f, second = -3.4e38f;
    int bi = 0;
#pragma unroll
    for (int q = 0; q < 8; ++q) {
        float4 v = s4[q];
        float vv[4] = {v.x, v.y, v.z, v.w};
#pragma unroll
        for (int e = 0; e < 4; ++e) {
            const int c = q * 4 + e;
            const float s = vv[e] + cb2[c];
            if (s > best) { second = best; best = s; bi = c; }
            else if (s > second) second = s;
        }
    }
    idx[row] = bi;
    if (best - second < REFINE_TH) {
        int slot = atomicAdd(rcnt, 1);
        if (slot < REFINE_CAP) rrows[slot] = row;
    }
}

// exact fp32 recompute of scores for flagged rows
__global__ __launch_bounds__(256) void k_refine_gemm(
    const float* __restrict__ K, const float* __restrict__ cw1,
    const float* __restrict__ cb1, const float* __restrict__ cw2,
    const int* __restrict__ rcnt, const int* __restrict__ rrows,
    float* __restrict__ scoresR)
{
    const int cnt = min(*rcnt, REFINE_CAP);
    if (cnt == 0) return;
    const int units = ((cnt + 63) >> 6) * 16;
    __shared__ float KsT[64][68];
    __shared__ float WsT[64][68];
    __shared__ float Hs2[64][68];
    __shared__ float W2f[NC][68];

    const int tid = threadIdx.x;
    const int ti = tid & 15, tj = tid >> 4;
    const int si = tid & 63, sc0 = (tid >> 6) * 8;

    for (int u = blockIdx.x; u < units; u += gridDim.x) {
        const int rc = u >> 4, jt = u & 15, j0 = jt * 64;
        const int M = min(cnt - rc * 64, 64);

        float hacc[4][4];
#pragma unroll
        for (int a = 0; a < 4; ++a)
#pragma unroll
            for (int b = 0; b < 4; ++b) hacc[a][b] = 0.f;

        for (int kt = 0; kt < 32; ++kt) {
            const int k0 = kt * 64;
            __syncthreads();
            {
                const int r  = tid >> 2;
                const int kb = (tid & 3) * 16;
                const int grow = rrows[rc * 64 + min(r, M - 1)];
#pragma unroll
                for (int q = 0; q < 4; ++q) {
                    float4 v = *(const float4*)&K[(size_t)grow * HDIM + k0 + kb + q * 4];
                    KsT[kb + q * 4 + 0][r] = v.x; KsT[kb + q * 4 + 1][r] = v.y;
                    KsT[kb + q * 4 + 2][r] = v.z; KsT[kb + q * 4 + 3][r] = v.w;
                }
                const int j = tid >> 2;
#pragma unroll
                for (int q = 0; q < 4; ++q) {
                    float4 v = *(const float4*)&cw1[(size_t)(j0 + j) * HDIM + k0 + kb + q * 4];
                    WsT[kb + q * 4 + 0][j] = v.x; WsT[kb + q * 4 + 1][j] = v.y;
                    WsT[kb + q * 4 + 2][j] = v.z; WsT[kb + q * 4 + 3][j] = v.w;
                }
            }
            __syncthreads();
#pragma unroll 4
            for (int k = 0; k < 64; ++k) {
                float4 a = *(float4*)&KsT[k][ti * 4];
                float4 b = *(float4*)&WsT[k][tj * 4];
                float av[4] = {a.x, a.y, a.z, a.w};
                float bv[4] = {b.x, b.y, b.z, b.w};
#pragma unroll
                for (int di = 0; di < 4; ++di)
#pragma unroll
                    for (int dj = 0; dj < 4; ++dj)
                        hacc[di][dj] += av[di] * bv[dj];
            }
        }
        __syncthreads();
#pragma unroll
        for (int di = 0; di < 4; ++di)
#pragma unroll
            for (int dj = 0; dj < 4; ++dj) {
                float h = hacc[di][dj] + cb1[j0 + tj * 4 + dj];
                Hs2[ti * 4 + di][tj * 4 + dj] = fmaxf(h, 0.f);
            }
        {
            const int c  = tid >> 3;
            const int jq = (tid & 7) * 8;
            *(float4*)&W2f[c][jq]     = *(const float4*)&cw2[(size_t)c * HHALF + j0 + jq];
            *(float4*)&W2f[c][jq + 4] = *(const float4*)&cw2[(size_t)c * HHALF + j0 + jq + 4];
        }
        __syncthreads();
        float sacc[8];
#pragma unroll
        for (int q = 0; q < 8; ++q) sacc[q] = 0.f;
        for (int j = 0; j < 64; ++j) {
            float h = Hs2[si][j];
#pragma unroll
            for (int q = 0; q < 8; ++q) sacc[q] += h * W2f[sc0 + q][j];
        }
        if (si < M) {
#pragma unroll
            for (int q = 0; q < 8; ++q)
                atomicAdd(&scoresR[(size_t)(rc * 64 + si) * NC + sc0 + q], sacc[q]);
        }
        __syncthreads();
    }
}

__global__ __launch_bounds__(256) void k_refine_fix(
    const int* __restrict__ rcnt, const int* __restrict__ rrows,
    const float* __restrict__ scoresR, const float* __restrict__ cb2,
    int* __restrict__ idx)
{
    const int cnt = min(*rcnt, REFINE_CAP);
    const int t = blockIdx.x * 256 + threadIdx.x;
    if (t >= cnt) return;
    float best = -3.4e38f;
    int bi = 0;
    for (int c = 0; c < NC; ++c) {
        float v = scoresR[(size_t)t * NC + c] + cb2[c];
        if (v > best) { best = v; bi = c; }
    }
    idx[rrows[t]] = bi;
}

__global__ __launch_bounds__(256) void k_counts(const int* __restrict__ idx,
                                                float* __restrict__ counts)
{
    __shared__ int hist[NC];
    if (threadIdx.x < NC) hist[threadIdx.x] = 0;
    __syncthreads();
    const int i = blockIdx.x * 256 + threadIdx.x;
    atomicAdd(&hist[idx[i]], 1);
    __syncthreads();
    if (threadIdx.x < NC)
        atomicAdd(&counts[threadIdx.x], (float)hist[threadIdx.x]);
}

__global__ void k_scan(const float* __restrict__ counts,
                       int* __restrict__ offsets, int* __restrict__ cursor)
{
    const int c = threadIdx.x;
    int off = 0;
    for (int j = 0; j < c; ++j) off += (int)counts[j];
    offsets[c] = off;
    cursor[c]  = off;
}

__global__ __launch_bounds__(256) void k_scatter(const int* __restrict__ idx,
                                                 int* __restrict__ cursor,
                                                 int* __restrict__ rowlist)
{
    const int r = blockIdx.x * 256 + threadIdx.x;
    const int c = idx[r];
    const int p = atomicAdd(&cursor[c], 1);
    rowlist[p] = r;
}

// gather-sum: grid (32c x 16 chunks, 2 col-halves), register accumulation
__global__ __launch_bounds__(256) void k_gather(
    const float* __restrict__ K, const float* __restrict__ V,
    const int* __restrict__ offsets, const float* __restrict__ counts,
    const int* __restrict__ rowlist, float* __restrict__ ksum,
    float* __restrict__ vsum)
{
    const int c     = blockIdx.x & 31;
    const int chunk = blockIdx.x >> 5;
    const int half  = blockIdx.y;
    const int col   = half * 1024 + threadIdx.x * 4;

    const int off = offsets[c];
    const int n   = (int)counts[c];
    const int i0  = off + ((chunk * n) >> 4);
    const int i1  = off + (((chunk + 1) * n) >> 4);

    float ak0 = 0.f, ak1 = 0.f, ak2 = 0.f, ak3 = 0.f;
    float av0 = 0.f, av1 = 0.f, av2 = 0.f, av3 = 0.f;
    for (int i = i0; i < i1; ++i) {
        const int r = rowlist[i];
        const float4 kv = *(const float4*)&K[(size_t)r * HDIM + col];
        const float4 vv = *(const float4*)&V[(size_t)r * HDIM + col];
        ak0 += kv.x; ak1 += kv.y; ak2 += kv.z; ak3 += kv.w;
        av0 += vv.x; av1 += vv.y; av2 += vv.z; av3 += vv.w;
    }
    if (i1 > i0) {
        float* kd = &ksum[(size_t)c * HDIM + col];
        float* vd = &vsum[(size_t)c * HDIM + col];
        atomicAdd(kd + 0, ak0); atomicAdd(kd + 1, ak1);
        atomicAdd(kd + 2, ak2); atomicAdd(kd + 3, ak3);
        atomicAdd(vd + 0, av0); atomicAdd(vd + 1, av1);
        atomicAdd(vd + 2, av2); atomicAdd(vd + 3, av3);
    }
}

__global__ __launch_bounds__(256) void k_final1(float* __restrict__ kc,
                                                float* __restrict__ vc,
                                                const float* __restrict__ counts)
{
    const int e = blockIdx.x * 256 + threadIdx.x;
    const int c = e >> 11;
    const float denom = fmaxf(counts[c], 1.f);
    kc[e] /= denom;
    vc[e] /= denom;
}

__global__ __launch_bounds__(256) void k_final2(
    float* __restrict__ kc, float* __restrict__ vc,
    const float* __restrict__ counts, const float* __restrict__ nk,
    const float* __restrict__ nv)
{
    const int e = blockIdx.x * 256 + threadIdx.x;
    const int c = e >> 11;
    const int h = e & 2047;
    if (counts[c] == 0.f) {
        int src = 0;
        float best = counts[0];
        for (int j = 1; j < NC; ++j) {
            float v = counts[j];
            if (v > best) { best = v; src = j; }
        }
        kc[e] = kc[src * HDIM + h] + 0.1f * nk[e];
        vc[e] = vc[src * HDIM + h] + 0.1f * nv[e];
    }
}

// split-K MLP layer over the 32 centroids: grid (jt=32, kv=2, ks=4).
// Each block: 32 rows x 64 cols, k-range 512, atomicAdd into O (pre-zeroed).
__global__ __launch_bounds__(256) void k_mlp_sk(
    const float* __restrict__ Xk, const float* __restrict__ Xv,
    const float* __restrict__ W, float* __restrict__ Ok,
    float* __restrict__ Ov)
{
    __shared__ float Xs[32][65];
    __shared__ float Wt[64][65];
    const float* X = blockIdx.y ? Xv : Xk;
    float* O       = blockIdx.y ? Ov : Ok;
    const int tid   = threadIdx.x;
    const int jbase = blockIdx.x * 64;
    const int kbase = blockIdx.z * 512;
    const int ti = tid & 7;
    const int tj = tid >> 3;
    float acc[4][2];
#pragma unroll
    for (int a = 0; a < 4; ++a) { acc[a][0] = 0.f; acc[a][1] = 0.f; }

    for (int kt = 0; kt < 8; ++kt) {
        const int k0 = kbase + kt * 64;
        __syncthreads();
        {
            const int f4 = tid & 15;
            const int r  = tid >> 4;
#pragma unroll
            for (int rr = 0; rr < 2; ++rr) {
                const int row = r + rr * 16;
                float4 xv = *(const float4*)&X[(size_t)row * HDIM + k0 + f4 * 4];
                Xs[row][f4 * 4 + 0] = xv.x; Xs[row][f4 * 4 + 1] = xv.y;
                Xs[row][f4 * 4 + 2] = xv.z; Xs[row][f4 * 4 + 3] = xv.w;
            }
#pragma unroll
            for (int rr = 0; rr < 4; ++rr) {
                const int row = r + rr * 16;
                float4 wv = *(const float4*)&W[(size_t)(jbase + row) * HDIM + k0 + f4 * 4];
                Wt[row][f4 * 4 + 0] = wv.x; Wt[row][f4 * 4 + 1] = wv.y;
                Wt[row][f4 * 4 + 2] = wv.z; Wt[row][f4 * 4 + 3] = wv.w;
            }
        }
        __syncthreads();
#pragma unroll 8
        for (int k = 0; k < 64; ++k) {
            float a[4], b[2];
#pragma unroll
            for (int d = 0; d < 4; ++d) a[d] = Xs[ti * 4 + d][k];
#pragma unroll
            for (int d = 0; d < 2; ++d) b[d] = Wt[tj * 2 + d][k];
#pragma unroll
            for (int d = 0; d < 4; ++d)
#pragma unroll
                for (int e2 = 0; e2 < 2; ++e2)
                    acc[d][e2] += a[d] * b[e2];
        }
    }
#pragma unroll
    for (int d = 0; d < 4; ++d)
#pragma unroll
        for (int e2 = 0; e2 < 2; ++e2) {
            const int i = ti * 4 + d;
            const int j = jbase + tj * 2 + e2;
            atomicAdd(&O[(size_t)i * HDIM + j], acc[d][e2]);
        }
}

// bias (+optional relu) epilogue over [32][2048] pair
__global__ __launch_bounds__(256) void k_bias_act(
    float* __restrict__ Ak, float* __restrict__ Av,
    const float* __restrict__ bias, int relu)
{
    const int e = blockIdx.x * 256 + threadIdx.x;  // 65536
    const int j = e & 2047;
    const float b = bias[j];
    float vk = Ak[e] + b;
    float vv = Av[e] + b;
    if (relu) { vk = fmaxf(vk, 0.f); vv = fmaxf(vv, 0.f); }
    Ak[e] = vk;
    Av[e] = vv;
}

__global__ __launch_bounds__(256) void k_out(
    const float* __restrict__ K, const float* __restrict__ V,
    const float* __restrict__ imp, const int* __restrict__ idx,
    const float* __restrict__ tck, const float* __restrict__ tcv,
    float* __restrict__ ok, float* __restrict__ ov)
{
    const size_t total = (size_t)NROWS * (HDIM / 4);
    for (size_t e = (size_t)blockIdx.x * 256 + threadIdx.x; e < total;
         e += (size_t)gridDim.x * 256) {
        const int r = (int)(e >> 9);
        const int q = (int)(e & 511);
        const bool pass = imp[r] > 0.1f;
        const int c = idx[r];
        const float4* sk = pass ? (const float4*)&K[(size_t)r * HDIM]
                                : (const float4*)&tck[(size_t)c * HDIM];
        const float4* sv = pass ? (const float4*)&V[(size_t)r * HDIM]
                                : (const float4*)&tcv[(size_t)c * HDIM];
        ((float4*)ok)[e] = sk[q];
        ((float4*)ov)[e] = sv[q];
    }
}

extern "C" void kernel_launch(void* const* d_in, const int* in_sizes, int n_in,
                              void* d_out, int out_size, void* d_ws,
                              size_t ws_size, hipStream_t stream)
{
    (void)in_sizes; (void)n_in; (void)out_size; (void)ws_size;
    const float* keys   = (const float*)d_in[0];
    const float* values = (const float*)d_in[1];
    const float* imp    = (const float*)d_in[2];
    const float* cw1    = (const float*)d_in[3];
    const float* cb1    = (const float*)d_in[4];
    const float* cw2    = (const float*)d_in[5];
    const float* cb2    = (const float*)d_in[6];
    const float* tw1    = (const float*)d_in[7];
    const float* tb1    = (const float*)d_in[8];
    const float* tw2    = (const float*)d_in[9];
    const float* tb2    = (const float*)d_in[10];
    const float* nk     = (const float*)d_in[11];
    const float* nv     = (const float*)d_in[12];

    char* ws = (char*)d_ws;
    int*   idx    = (int*)ws;
    float* counts = (float*)(ws + (64 << 10));
    float* kcent  = (float*)(ws + (128 << 10));
    float* vcent  = (float*)(ws + (384 << 10));
    float* hk     = (float*)(ws + (640 << 10));
    float* hv     = (float*)(ws + (896 << 10));
    float* tck    = (float*)(ws + (1152 << 10));
    float* tcv    = (float*)(ws + (1408 << 10));

    const size_t MB = (size_t)1 << 20;
    char* ob = (char*)d_out;
    short* kh   = (short*)(ob);
    short* hidH = (short*)(ob + 128 * MB);
    short* w1h  = (short*)(ob + 192 * MB);
    short* w2h  = (short*)(ob + 200 * MB);
    float* scoresAll = (float*)(ob + 201 * MB);
    char*  sb = ob + 204 * MB;
    int*   offsets = (int*)(sb);
    int*   cursor  = (int*)(sb + 128);
    int*   rcnt    = (int*)(sb + 256);
    int*   rrows   = (int*)(sb + 1024);
    int*   rowlist = (int*)(sb + (80 << 10));
    float* scoresR = (float*)(sb + (256 << 10));
    float* ok = (float*)d_out;
    float* ov = ok + (size_t)NROWS * HDIM;

    // zero atomic targets: counts,kcent,vcent,hk,hv,tck,tcv + rcnt/scoresR
    hipMemsetAsync(ws + (64 << 10), 0, (1664 - 64) << 10, stream);
    hipMemsetAsync(sb, 0, (256 << 10) + 2 * MB, stream);

    k_split_h<<<2048, 256, 0, stream>>>(keys, kh, NROWS * HDIM / 8);
    k_split_h<<<256, 256, 0, stream>>>(cw1, w1h, HHALF * HDIM / 8);
    k_split_h<<<16, 256, 0, stream>>>(cw2, w2h, NC * HHALF / 8);
    k_gemm1<<<1024, 256, 0, stream>>>(kh, w1h, cb1, hidH);
    k_gemm2<<<NROWS / 64, 256, 0, stream>>>(hidH, w2h, scoresAll);
    k_argmax<<<NROWS / 256, 256, 0, stream>>>(scoresAll, cb2, idx, rcnt, rrows);
    k_refine_gemm<<<256, 256, 0, stream>>>(keys, cw1, cb1, cw2, rcnt, rrows, scoresR);
    k_refine_fix<<<NROWS / 256, 256, 0, stream>>>(rcnt, rrows, scoresR, cb2, idx);
    k_counts<<<NROWS / 256, 256, 0, stream>>>(idx, counts);
    k_scan<<<1, 32, 0, stream>>>(counts, offsets, cursor);
    k_scatter<<<NROWS / 256, 256, 0, stream>>>(idx, cursor, rowlist);
    k_gather<<<dim3(32 * 16, 2), 256, 0, stream>>>(keys, values, offsets, counts,
                                                   rowlist, kcent, vcent);
    k_final1<<<(NC * HDIM) / 256, 256, 0, stream>>>(kcent, vcent, counts);
    k_final2<<<(NC * HDIM) / 256, 256, 0, stream>>>(kcent, vcent, counts, nk, nv);
    k_mlp_sk<<<dim3(32, 2, 4), 256, 0, stream>>>(kcent, vcent, tw1, hk, hv);
    k_bias_act<<<256, 256, 0, stream>>>(hk, hv, tb1, 1);
    k_mlp_sk<<<dim3(32, 2, 4), 256, 0, stream>>>(hk, hv, tw2, tck, tcv);
    k_bias_act<<<256, 256, 0, stream>>>(tck, tcv, tb2, 0);
    k_out<<<2048, 256, 0, stream>>>(keys, values, imp, idx, tck, tcv, ok, ov);
}